// Round 9
// baseline (167.563 us; speedup 1.0000x reference)
//
#include <hip/hip_runtime.h>

typedef short bf16x8 __attribute__((ext_vector_type(8), may_alias));
typedef float f32x4 __attribute__((ext_vector_type(4)));
typedef unsigned int u32x4a __attribute__((ext_vector_type(4), may_alias));
typedef unsigned int u32x2a __attribute__((ext_vector_type(2), may_alias));
typedef unsigned short ushort;
typedef unsigned int uint;

#define B_N 4
#define H_N 16
#define S_N 2048
#define D_N 64
#define BQ 128      // q rows per block
#define WQ 32       // q rows per wave
#define KT 64       // key tile in the image / fallback kernel
#define NW 4        // waves per block
#define NBLK (B_N*H_N*(S_N/BQ))   // 1024 blocks
#define TILE_BYTES 32768          // image tile: Khi|Klo|VThi|VTlo, 8KB each (64 keys)
#define MAXTILE (S_N/KT)          // 32
#define IMG_OFF 32768
#define WS_NEED ((size_t)IMG_OFF + (size_t)B_N*H_N*MAXTILE*TILE_BYTES)

#define MFMA16 __builtin_amdgcn_mfma_f32_16x16x32_bf16

// f32 -> bf16 round-to-nearest-even (bit trick)
__device__ __forceinline__ uint f2bf(float x){
  uint u = __float_as_uint(x);
  u += 0x7fffu + ((u >> 16) & 1u);
  return u >> 16;
}
__device__ __forceinline__ float bf2f(uint h){
  return __uint_as_float(h << 16);
}
__device__ __forceinline__ int ldsw(int off, int row){
  return off ^ ((row & 7) << 4);
}
__device__ __forceinline__ void gload16(const void* g, void* l){
  __builtin_amdgcn_global_load_lds((const uint __attribute__((address_space(1)))*)g,
                                   (uint __attribute__((address_space(3)))*)l, 16, 0, 0);
}

// ---------------- pre-pass A: per-b mask compaction ----------------
__global__ __launch_bounds__(256)
void compact_k(const int* __restrict__ Mg, int* __restrict__ cnt_ws,
               ushort* __restrict__ idx_ws)
{
  __shared__ int sws[NW];
  const int b = blockIdx.x;
  const int tid = threadIdx.x, lane = tid & 63, w = tid >> 6;
  const int* mb = Mg + (size_t)b * S_N;
  int kept[8]; int cl = 0; int base = tid * 8;
  #pragma unroll
  for (int i = 0; i < 8; ++i){ kept[i] = (mb[base+i] == 0); cl += kept[i]; }
  int inc = cl;
  #pragma unroll
  for (int d = 1; d < 64; d <<= 1){
    int o = __shfl_up(inc, d);
    if (lane >= d) inc += o;
  }
  if (lane == 63) sws[w] = inc;
  __syncthreads();
  int s0 = sws[0], s1 = sws[1], s2 = sws[2], s3 = sws[3];
  int wo = (w > 0 ? s0 : 0) + (w > 1 ? s1 : 0) + (w > 2 ? s2 : 0);
  int pos = wo + inc - cl;
  #pragma unroll
  for (int i = 0; i < 8; ++i){
    if (kept[i]) idx_ws[b*S_N + pos++] = (ushort)(base + i);
  }
  if (tid == 0) cnt_ws[b] = s0 + s1 + s2 + s3;
}

// ---------------- pre-pass B: gather + convert + build images ----------------
// K image (per 64-key tile): rows jrow*128B, 16B granules XOR-swizzled by (jrow&7)
// (staged into LDS via global_load_lds, round-5 proven).
// V^T image: GRANULE-TRANSPOSED (round-6 proven, read direct from L2):
//   granule(g=0..3, h=0..1, d=0..63) at 16384 + g*2048 + h*1024 + d*16 (hi)
//   and +8192 for lo; elements e = V[h*32 + kap(g,e)][d],
//   kap(g,e) = g*4+(e&3)+16*(e>>2) -- matches MFMA C-layout so P is a bitcast.
__global__ __launch_bounds__(256)
void stage_k(const float* __restrict__ Kg, const float* __restrict__ Vg,
             const int* __restrict__ cnt_ws, const ushort* __restrict__ idx_ws,
             char* __restrict__ img)
{
  __shared__ float Vl[64*65];
  const int bid = blockIdx.x;
  const int bh = bid >> 5;
  const int tile = bid & 31;
  const int b = bh >> 4;
  const int cnt = cnt_ws[b];
  const int ntile = (cnt + 63) >> 6;
  if (tile >= ntile) return;
  const int tid = threadIdx.x;
  char* G = img + (size_t)bid * TILE_BYTES;

  const int jrow = tid >> 2, c4 = tid & 3;
  int kk = tile*64 + jrow; if (kk >= cnt) kk = cnt - 1;
  const int sidx = idx_ws[b*S_N + kk];
  const size_t kvbase = (size_t)bh * (size_t)(S_N*D_N);
  const int sw = (jrow & 7) << 4;
  {
    const float4* Kp = (const float4*)(Kg + kvbase + (size_t)sidx*D_N) + c4*4;
    float4 k0 = Kp[0], k1 = Kp[1], k2 = Kp[2], k3 = Kp[3];
    float kv[16] = {k0.x,k0.y,k0.z,k0.w,k1.x,k1.y,k1.z,k1.w,
                    k2.x,k2.y,k2.z,k2.w,k3.x,k3.y,k3.z,k3.w};
    uint h[16], l[16];
    #pragma unroll
    for (int e = 0; e < 16; ++e){
      uint hh = f2bf(kv[e]); h[e] = hh; l[e] = f2bf(kv[e] - bf2f(hh));
    }
    char* r0 = G + jrow*128;
    char* r1 = G + 8192 + jrow*128;
    *(u32x4a*)(r0 + ((c4*32)      ^ sw)) = (u32x4a){h[0]|(h[1]<<16),  h[2]|(h[3]<<16),
                                                    h[4]|(h[5]<<16),  h[6]|(h[7]<<16)};
    *(u32x4a*)(r0 + ((c4*32 + 16) ^ sw)) = (u32x4a){h[8]|(h[9]<<16),  h[10]|(h[11]<<16),
                                                    h[12]|(h[13]<<16),h[14]|(h[15]<<16)};
    *(u32x4a*)(r1 + ((c4*32)      ^ sw)) = (u32x4a){l[0]|(l[1]<<16),  l[2]|(l[3]<<16),
                                                    l[4]|(l[5]<<16),  l[6]|(l[7]<<16)};
    *(u32x4a*)(r1 + ((c4*32 + 16) ^ sw)) = (u32x4a){l[8]|(l[9]<<16),  l[10]|(l[11]<<16),
                                                    l[12]|(l[13]<<16),l[14]|(l[15]<<16)};
  }
  {
    const float4* Vp = (const float4*)(Vg + kvbase + (size_t)sidx*D_N) + c4*4;
    float4 v0 = Vp[0], v1 = Vp[1], v2 = Vp[2], v3 = Vp[3];
    float vv[16] = {v0.x,v0.y,v0.z,v0.w,v1.x,v1.y,v1.z,v1.w,
                    v2.x,v2.y,v2.z,v2.w,v3.x,v3.y,v3.z,v3.w};
    #pragma unroll
    for (int e = 0; e < 16; ++e) Vl[jrow*65 + c4*16 + e] = vv[e];
  }
  __syncthreads();
  // V^T granules with kap ordering, granule-transposed placement (round-6 layout)
  #pragma unroll
  for (int t = 0; t < 2; ++t){
    int idx2 = tid + t*256;
    int d = idx2 >> 3;
    int h = (idx2 >> 2) & 1;
    int g = idx2 & 3;
    int kb = h*32 + g*4;
    uint hh[8], ll[8];
    #pragma unroll
    for (int e = 0; e < 8; ++e){
      int k = kb + (e & 3) + ((e >> 2) << 4);   // kap(g,e) within half
      float x = Vl[k*65 + d];
      uint hv = f2bf(x); hh[e] = hv; ll[e] = f2bf(x - bf2f(hv));
    }
    *(u32x4a*)(G + 16384 + g*2048 + h*1024 + d*16) =
        (u32x4a){hh[0]|(hh[1]<<16), hh[2]|(hh[3]<<16), hh[4]|(hh[5]<<16), hh[6]|(hh[7]<<16)};
    *(u32x4a*)(G + 24576 + g*2048 + h*1024 + d*16) =
        (u32x4a){ll[0]|(ll[1]<<16), ll[2]|(ll[3]<<16), ll[4]|(ll[5]<<16), ll[6]|(ll[7]<<16)};
  }
}

// ---------------- main attention kernel: round-5 math + V-direct ----------------
// K double-buffered in LDS (16KB total); V fragments read DIRECTLY from the
// L2-resident image (round-6-proven pattern) -- values and contraction order
// are bitwise identical to round 5; only the memory path for V changed.
__global__ __launch_bounds__(256, 2)
void attn9_k(const float* __restrict__ Qg, const char* __restrict__ img,
             const int* __restrict__ cnt_ws, float* __restrict__ Og)
{
  __shared__ __align__(16) char smem[2][8192];   // [buf][Khi 4KB | Klo 4KB]

  const int tid  = threadIdx.x;
  const int lane = tid & 63;
  const int w    = tid >> 6;
  const int c    = lane & 15;
  const int gi   = lane >> 4;

  int bid = blockIdx.x;
  int wg  = (bid & 7) * (NBLK/8) + (bid >> 3);
  int qt  = wg & 15;
  int bh  = wg >> 4;
  int b   = bh >> 4;

  const int cnt = cnt_ws[b];
  const int nhalf = (cnt + 31) >> 5;
  const char* Gb = img + (size_t)bh * MAXTILE * TILE_BYTES;

  // stage K half-tile hidx into buffer sb (waves 0,1 only)
  auto stage = [&](int hidx, int sb){
    if (w < 2){
      const char* T = Gb + (size_t)(hidx >> 1) * TILE_BYTES;
      const int h = hidx & 1;
      const char* src = T + w*8192 + h*4096 + lane*16;
      char* dst = (char*)&smem[sb][0] + w*4096;
      #pragma unroll
      for (int i = 0; i < 4; ++i) gload16(src + i*1024, dst + i*1024);
    }
  };

  if (nhalf > 0) stage(0, 0);

  // Q fragments hi/lo in registers (B-operand of swapped QK^T)
  const int q0w = qt * BQ + w * WQ;
  bf16x8 qh[2][2], ql[2][2];
  {
    const float* Qbase = Qg + (size_t)bh * S_N * D_N;
    #pragma unroll
    for (int qs = 0; qs < 2; ++qs){
      const float* qr = Qbase + (size_t)(q0w + qs*16 + c) * D_N;
      #pragma unroll
      for (int ks = 0; ks < 2; ++ks){
        const float4* p4 = (const float4*)(qr + ks*32 + gi*8);
        float4 x0 = p4[0], x1 = p4[1];
        float xs[8] = {x0.x,x0.y,x0.z,x0.w,x1.x,x1.y,x1.z,x1.w};
        union { bf16x8 v; ushort u[8]; } uh, ul;
        #pragma unroll
        for (int e = 0; e < 8; ++e){
          uint h = f2bf(xs[e]);
          uh.u[e] = (ushort)h;
          ul.u[e] = (ushort)f2bf(xs[e] - bf2f(h));
        }
        qh[qs][ks] = uh.v; ql[qs][ks] = ul.v;
      }
    }
  }

  f32x4 Oa[2][4];
  #pragma unroll
  for (int i = 0; i < 2; ++i)
    #pragma unroll
    for (int jj = 0; jj < 4; ++jj)
      Oa[i][jj] = (f32x4){0.f,0.f,0.f,0.f};
  float zz[2] = {0.f, 0.f};

  const int swc16 = (c & 7) << 4;
  const int e0 = (gi*16) ^ swc16;
  const int e1 = (64 + gi*16) ^ swc16;

  __syncthreads();

  for (int tb = 0; tb < nhalf; ++tb){
    const int buf = tb & 1;
    if (tb + 1 < nhalf) stage(tb + 1, buf ^ 1);
    const char* Khi  = &smem[buf][0];
    const char* Klo  = Khi + 4096;
    // V granule base: direct from image (round-6 pattern)
    const char* VB = Gb + (size_t)(tb >> 1) * TILE_BYTES + 16384
                     + gi*2048 + (tb & 1)*1024 + c*16;
    const bool lastt = (tb == nhalf - 1);

    uint sH[2][4], sL[2][4];   // [qs][hA_kt0,hB_kt0,hA_kt1,hB_kt1]
    #pragma unroll
    for (int kt = 0; kt < 2; ++kt){
      int row = kt*16 + c;
      const char* krh = Khi + row*128;
      const char* krl = Klo + row*128;
      bf16x8 kh0 = *(const bf16x8*)(krh + e0);
      bf16x8 kh1 = *(const bf16x8*)(krh + e1);
      bf16x8 kl0 = *(const bf16x8*)(krl + e0);
      bf16x8 kl1 = *(const bf16x8*)(krl + e1);
      #pragma unroll
      for (int qs = 0; qs < 2; ++qs){
        f32x4 s = (f32x4){0.f,0.f,0.f,0.f};
        s = MFMA16(kh0, qh[qs][0], s, 0,0,0);
        s = MFMA16(kh1, qh[qs][1], s, 0,0,0);
        s = MFMA16(kh0, ql[qs][0], s, 0,0,0);
        s = MFMA16(kh1, ql[qs][1], s, 0,0,0);
        s = MFMA16(kl0, qh[qs][0], s, 0,0,0);
        s = MFMA16(kl1, qh[qs][1], s, 0,0,0);
        // p = exp(10*tanh(s/8) - 10) = exp2(-28.8539 / (exp2(s*0.360674)+1))
        float pv[4];
        #pragma unroll
        for (int r = 0; r < 4; ++r){
          float t  = __builtin_amdgcn_exp2f(s[r] * 0.3606737602222409f);
          float wv = __builtin_amdgcn_rcpf(t + 1.0f);
          pv[r] = __builtin_amdgcn_exp2f(-28.853900817779268f * wv);
        }
        if (lastt){
          int kg0 = tb*32 + kt*16 + gi*4;
          #pragma unroll
          for (int r = 0; r < 4; ++r) if (kg0 + r >= cnt) pv[r] = 0.f;
        }
        zz[qs] += (pv[0] + pv[1]) + (pv[2] + pv[3]);
        uint hA, hB, lA, lB;
        asm("v_cvt_pk_bf16_f32 %0, %1, %2" : "=v"(hA) : "v"(pv[0]), "v"(pv[1]));
        asm("v_cvt_pk_bf16_f32 %0, %1, %2" : "=v"(hB) : "v"(pv[2]), "v"(pv[3]));
        float l0 = pv[0] - __uint_as_float(hA << 16);
        float l1 = pv[1] - __uint_as_float(hA & 0xffff0000u);
        float l2 = pv[2] - __uint_as_float(hB << 16);
        float l3 = pv[3] - __uint_as_float(hB & 0xffff0000u);
        asm("v_cvt_pk_bf16_f32 %0, %1, %2" : "=v"(lA) : "v"(l0), "v"(l1));
        asm("v_cvt_pk_bf16_f32 %0, %1, %2" : "=v"(lB) : "v"(l2), "v"(l3));
        sH[qs][kt*2+0] = hA; sH[qs][kt*2+1] = hB;
        sL[qs][kt*2+0] = lA; sL[qs][kt*2+1] = lB;
      }
    }
    // P fragments: pure bitcast (k-order kap matches the V^T image)
    union PU { u32x4a g; bf16x8 v; };
    PU pah[2], pal[2];
    #pragma unroll
    for (int qs = 0; qs < 2; ++qs){
      pah[qs].g = (u32x4a){sH[qs][0], sH[qs][1], sH[qs][2], sH[qs][3]};
      pal[qs].g = (u32x4a){sL[qs][0], sL[qs][1], sL[qs][2], sL[qs][3]};
    }
    #pragma unroll
    for (int ds = 0; ds < 4; ++ds){
      bf16x8 vh = *(const bf16x8*)(VB + ds*256);
      bf16x8 vl = *(const bf16x8*)(VB + 8192 + ds*256);
      #pragma unroll
      for (int qs = 0; qs < 2; ++qs){
        f32x4 o = Oa[qs][ds];
        o = MFMA16(pah[qs].v, vh, o, 0,0,0);
        o = MFMA16(pah[qs].v, vl, o, 0,0,0);
        o = MFMA16(pal[qs].v, vh, o, 0,0,0);
        Oa[qs][ds] = o;
      }
    }
    __syncthreads();
  }

  // ---------- epilogue ----------
  #pragma unroll
  for (int qs = 0; qs < 2; ++qs){
    float zt = zz[qs];
    zt += __shfl_xor(zt, 16);
    zt += __shfl_xor(zt, 32);
    float rz = 1.0f / zt;
    #pragma unroll
    for (int r = 0; r < 4; ++r){
      float rzq = __shfl(rz, gi*4 + r);
      size_t rowbase = ((size_t)bh * S_N + (size_t)(q0w + qs*16 + gi*4 + r)) * D_N;
      #pragma unroll
      for (int ds = 0; ds < 4; ++ds){
        Og[rowbase + ds*16 + c] = Oa[qs][ds][r] * rzq;
      }
    }
  }
}

// ---------------- fallback (round-1 kernel, self-staging) ----------------
__global__ __launch_bounds__(256, 2)
void attn_k(const float* __restrict__ Qg, const float* __restrict__ Kg,
            const float* __restrict__ Vg, const int* __restrict__ Mg,
            float* __restrict__ Og)
{
  __shared__ __align__(16) ushort Khi[KT*D_N];
  __shared__ __align__(16) ushort Klo[KT*D_N];
  __shared__ __align__(16) ushort Vhi[D_N*72];
  __shared__ __align__(16) ushort Vlo[D_N*72];
  __shared__ __align__(16) ushort Phl[NW*16*72];
  __shared__ __align__(16) ushort Pll[NW*16*72];
  __shared__ ushort idx_l[S_N];
  __shared__ int scan_ws[NW];

  const int tid  = threadIdx.x;
  const int lane = tid & 63;
  const int w    = tid >> 6;
  const int c    = lane & 15;
  const int gi   = lane >> 4;

  int bid = blockIdx.x;
  int wg  = (bid & 7) * (NBLK/8) + (bid >> 3);
  int qt  = wg & 15;
  int bh  = wg >> 4;
  int b   = bh >> 4;

  int cnt;
  {
    const int* mb = Mg + (size_t)b * S_N;
    int kept[8]; int cl = 0;
    int base = tid * 8;
    #pragma unroll
    for (int i = 0; i < 8; ++i){ kept[i] = (mb[base+i] == 0); cl += kept[i]; }
    int inc = cl;
    #pragma unroll
    for (int d = 1; d < 64; d <<= 1){
      int o = __shfl_up(inc, d);
      if (lane >= d) inc += o;
    }
    if (lane == 63) scan_ws[w] = inc;
    __syncthreads();
    int s0 = scan_ws[0], s1 = scan_ws[1], s2 = scan_ws[2], s3 = scan_ws[3];
    int wo = (w > 0 ? s0 : 0) + (w > 1 ? s1 : 0) + (w > 2 ? s2 : 0);
    cnt = s0 + s1 + s2 + s3;
    int pos = wo + inc - cl;
    #pragma unroll
    for (int i = 0; i < 8; ++i){
      if (kept[i]) idx_l[pos++] = (ushort)(base + i);
    }
    __syncthreads();
  }

  const int q0w = qt * BQ + w * WQ;
  bf16x8 qh[2][2], ql[2][2];
  {
    const float* Qbase = Qg + (size_t)bh * S_N * D_N;
    #pragma unroll
    for (int qs = 0; qs < 2; ++qs){
      const float* qr = Qbase + (size_t)(q0w + qs*16 + c) * D_N;
      #pragma unroll
      for (int ks = 0; ks < 2; ++ks){
        const float4* p4 = (const float4*)(qr + ks*32 + gi*8);
        float4 x0 = p4[0], x1 = p4[1];
        float xs[8] = {x0.x,x0.y,x0.z,x0.w,x1.x,x1.y,x1.z,x1.w};
        union { bf16x8 v; ushort u[8]; } uh, ul;
        #pragma unroll
        for (int e = 0; e < 8; ++e){
          uint h = f2bf(xs[e]);
          uh.u[e] = (ushort)h;
          ul.u[e] = (ushort)f2bf(xs[e] - bf2f(h));
        }
        qh[qs][ks] = uh.v; ql[qs][ks] = ul.v;
      }
    }
  }

  f32x4 Oa[2][4];
  #pragma unroll
  for (int i = 0; i < 2; ++i)
    #pragma unroll
    for (int jj = 0; jj < 4; ++jj)
      Oa[i][jj] = (f32x4){0.f,0.f,0.f,0.f};
  float zz[2] = {0.f, 0.f};

  ushort* Ph = Phl + w * (16*72);
  ushort* Pl = Pll + w * (16*72);

  const int jrow = tid >> 2;
  const int c4   = tid & 3;
  const size_t kvbase = (size_t)bh * S_N * D_N;

  const int ntile = (cnt + KT - 1) >> 6;
  for (int tb = 0; tb < ntile; ++tb){
    {
      int kk = tb*KT + jrow;
      int ci = kk < cnt ? kk : cnt - 1;
      int sidx = idx_l[ci];
      const float4* Kp = (const float4*)(Kg + kvbase + (size_t)sidx * D_N) + c4*4;
      const float4* Vp = (const float4*)(Vg + kvbase + (size_t)sidx * D_N) + c4*4;
      float4 k0 = Kp[0], k1 = Kp[1], k2 = Kp[2], k3 = Kp[3];
      float kv[16] = {k0.x,k0.y,k0.z,k0.w,k1.x,k1.y,k1.z,k1.w,
                      k2.x,k2.y,k2.z,k2.w,k3.x,k3.y,k3.z,k3.w};
      uint kh[16], klv[16];
      #pragma unroll
      for (int e = 0; e < 16; ++e){
        uint h = f2bf(kv[e]);
        kh[e] = h; klv[e] = f2bf(kv[e] - bf2f(h));
      }
      u32x4a H0 = (u32x4a){kh[0]|(kh[1]<<16),   kh[2]|(kh[3]<<16),
                           kh[4]|(kh[5]<<16),   kh[6]|(kh[7]<<16)};
      u32x4a H1 = (u32x4a){kh[8]|(kh[9]<<16),   kh[10]|(kh[11]<<16),
                           kh[12]|(kh[13]<<16), kh[14]|(kh[15]<<16)};
      u32x4a L0 = (u32x4a){klv[0]|(klv[1]<<16),   klv[2]|(klv[3]<<16),
                           klv[4]|(klv[5]<<16),   klv[6]|(klv[7]<<16)};
      u32x4a L1 = (u32x4a){klv[8]|(klv[9]<<16),   klv[10]|(klv[11]<<16),
                           klv[12]|(klv[13]<<16), klv[14]|(klv[15]<<16)};
      char* krh = (char*)Khi + jrow*128;
      char* krl = (char*)Klo + jrow*128;
      int o0 = ldsw(c4*32, jrow), o1 = ldsw(c4*32 + 16, jrow);
      *(u32x4a*)(krh + o0) = H0;  *(u32x4a*)(krh + o1) = H1;
      *(u32x4a*)(krl + o0) = L0;  *(u32x4a*)(krl + o1) = L1;

      float4 v0 = Vp[0], v1 = Vp[1], v2 = Vp[2], v3 = Vp[3];
      float vv[16] = {v0.x,v0.y,v0.z,v0.w,v1.x,v1.y,v1.z,v1.w,
                      v2.x,v2.y,v2.z,v2.w,v3.x,v3.y,v3.z,v3.w};
      #pragma unroll
      for (int e = 0; e < 16; ++e){
        int d = c4*16 + e;
        uint h  = f2bf(vv[e]);
        uint l2 = f2bf(vv[e] - bf2f(h));
        int off = d*144 + ldsw(jrow*2, d);
        *(ushort*)((char*)Vhi + off) = (ushort)h;
        *(ushort*)((char*)Vlo + off) = (ushort)l2;
      }
    }
    __syncthreads();

    const bool lastt = (tb == ntile - 1);
    #pragma unroll
    for (int qs = 0; qs < 2; ++qs){
      #pragma unroll
      for (int kt = 0; kt < 4; ++kt){
        int row = kt*16 + c;
        const char* krh = (const char*)Khi + row*128;
        const char* krl = (const char*)Klo + row*128;
        int e0 = ldsw(16*gi, row), e1 = ldsw(64 + 16*gi, row);
        bf16x8 kh0 = *(const bf16x8*)(krh + e0);
        bf16x8 kh1 = *(const bf16x8*)(krh + e1);
        bf16x8 kl0 = *(const bf16x8*)(krl + e0);
        bf16x8 kl1 = *(const bf16x8*)(krl + e1);
        f32x4 s = (f32x4){0.f,0.f,0.f,0.f};
        s = MFMA16(kh0, qh[qs][0], s, 0,0,0);
        s = MFMA16(kh1, qh[qs][1], s, 0,0,0);
        s = MFMA16(kh0, ql[qs][0], s, 0,0,0);
        s = MFMA16(kh1, ql[qs][1], s, 0,0,0);
        s = MFMA16(kl0, qh[qs][0], s, 0,0,0);
        s = MFMA16(kl1, qh[qs][1], s, 0,0,0);
        float pv[4];
        #pragma unroll
        for (int r = 0; r < 4; ++r){
          float t  = __builtin_amdgcn_exp2f(s[r] * 0.3606737602222409f);
          float wv = __builtin_amdgcn_rcpf(t + 1.0f);
          pv[r] = __builtin_amdgcn_exp2f(-28.853900817779268f * wv);
        }
        if (lastt){
          int kg0 = tb*KT + kt*16 + gi*4;
          #pragma unroll
          for (int r = 0; r < 4; ++r) if (kg0 + r >= cnt) pv[r] = 0.f;
        }
        zz[qs] += (pv[0] + pv[1]) + (pv[2] + pv[3]);
        uint h0 = f2bf(pv[0]), h1 = f2bf(pv[1]),
             h2 = f2bf(pv[2]), h3 = f2bf(pv[3]);
        uint l0 = f2bf(pv[0]-bf2f(h0)), l1 = f2bf(pv[1]-bf2f(h1)),
             l2 = f2bf(pv[2]-bf2f(h2)), l3 = f2bf(pv[3]-bf2f(h3));
        int ow = c*144 + ldsw(kt*32 + gi*8, c);
        *(u32x2a*)((char*)Ph + ow) = (u32x2a){h0|(h1<<16), h2|(h3<<16)};
        *(u32x2a*)((char*)Pl + ow) = (u32x2a){l0|(l1<<16), l2|(l3<<16)};
      }
      bf16x8 pah[2], pal[2];
      {
        const char* prh = (const char*)Ph + c*144;
        const char* prl = (const char*)Pl + c*144;
        #pragma unroll
        for (int ks = 0; ks < 2; ++ks){
          int oo = ldsw(64*ks + 16*gi, c);
          pah[ks] = *(const bf16x8*)(prh + oo);
          pal[ks] = *(const bf16x8*)(prl + oo);
        }
      }
      #pragma unroll
      for (int ds = 0; ds < 4; ++ds){
        int drow = ds*16 + c;
        const char* vrh = (const char*)Vhi + drow*144;
        const char* vrl = (const char*)Vlo + drow*144;
        f32x4 o = Oa[qs][ds];
        #pragma unroll
        for (int ks = 0; ks < 2; ++ks){
          int oo = ldsw(64*ks + 16*gi, drow);
          bf16x8 vh = *(const bf16x8*)(vrh + oo);
          bf16x8 vl = *(const bf16x8*)(vrl + oo);
          o = MFMA16(pah[ks], vh, o, 0,0,0);
          o = MFMA16(pah[ks], vl, o, 0,0,0);
          o = MFMA16(pal[ks], vh, o, 0,0,0);
        }
        Oa[qs][ds] = o;
      }
    }
    __syncthreads();
  }

  #pragma unroll
  for (int qs = 0; qs < 2; ++qs){
    float zt = zz[qs];
    zt += __shfl_xor(zt, 16);
    zt += __shfl_xor(zt, 32);
    float rz = 1.0f / zt;
    #pragma unroll
    for (int r = 0; r < 4; ++r){
      float rzq = __shfl(rz, gi*4 + r);
      size_t rowbase = ((size_t)bh * S_N + (size_t)(q0w + qs*16 + gi*4 + r)) * D_N;
      #pragma unroll
      for (int ds = 0; ds < 4; ++ds){
        Og[rowbase + ds*16 + c] = Oa[qs][ds][r] * rzq;
      }
    }
  }
}

extern "C" void kernel_launch(void* const* d_in, const int* in_sizes, int n_in,
                              void* d_out, int out_size, void* d_ws, size_t ws_size,
                              hipStream_t stream) {
  const float* Qg = (const float*)d_in[0];
  const float* Kg = (const float*)d_in[1];
  const float* Vg = (const float*)d_in[2];
  const int*   Mg = (const int*)d_in[3];
  float* Og = (float*)d_out;
  if (ws_size >= WS_NEED){
    int*    cnt_ws = (int*)d_ws;
    ushort* idx_ws = (ushort*)((char*)d_ws + 64);
    char*   img    = (char*)d_ws + IMG_OFF;
    compact_k<<<dim3(B_N), dim3(256), 0, stream>>>(Mg, cnt_ws, idx_ws);
    stage_k<<<dim3(B_N*H_N*MAXTILE), dim3(256), 0, stream>>>(Kg, Vg, cnt_ws, idx_ws, img);
    attn9_k<<<dim3(NBLK), dim3(256), 0, stream>>>(Qg, img, cnt_ws, Og);
  } else {
    attn_k<<<dim3(NBLK), dim3(256), 0, stream>>>(Qg, Kg, Vg, Mg, Og);
  }
}

// Round 10
// 145.556 us; speedup vs baseline: 1.1512x; 1.1512x over previous
//
#include <hip/hip_runtime.h>

typedef short bf16x8 __attribute__((ext_vector_type(8), may_alias));
typedef float f32x4 __attribute__((ext_vector_type(4)));
typedef unsigned int u32x4a __attribute__((ext_vector_type(4), may_alias));
typedef unsigned int u32x2a __attribute__((ext_vector_type(2), may_alias));
typedef unsigned short ushort;
typedef unsigned int uint;

#define B_N 4
#define H_N 16
#define S_N 2048
#define D_N 64
#define BQ 128      // q rows per block
#define WQ 32       // q rows per wave
#define KT 64       // key tile in the image / fallback kernel
#define NW 4        // waves per block
#define NBLK (B_N*H_N*(S_N/BQ))   // 1024 blocks
#define TILE_BYTES 32768          // image tile: Khi|Klo|VThi|VTlo, 8KB each (64 keys)
#define MAXTILE (S_N/KT)          // 32
#define IMG_OFF 32768
#define WS_NEED ((size_t)IMG_OFF + (size_t)B_N*H_N*MAXTILE*TILE_BYTES)

#define MFMA16 __builtin_amdgcn_mfma_f32_16x16x32_bf16

// f32 -> bf16 round-to-nearest-even (bit trick)
__device__ __forceinline__ uint f2bf(float x){
  uint u = __float_as_uint(x);
  u += 0x7fffu + ((u >> 16) & 1u);
  return u >> 16;
}
__device__ __forceinline__ float bf2f(uint h){
  return __uint_as_float(h << 16);
}
__device__ __forceinline__ int ldsw(int off, int row){
  return off ^ ((row & 7) << 4);
}
__device__ __forceinline__ void gload16(const void* g, void* l){
  __builtin_amdgcn_global_load_lds((const uint __attribute__((address_space(1)))*)g,
                                   (uint __attribute__((address_space(3)))*)l, 16, 0, 0);
}

// ---------------- pre-pass A: per-b mask compaction ----------------
__global__ __launch_bounds__(256)
void compact_k(const int* __restrict__ Mg, int* __restrict__ cnt_ws,
               ushort* __restrict__ idx_ws)
{
  __shared__ int sws[NW];
  const int b = blockIdx.x;
  const int tid = threadIdx.x, lane = tid & 63, w = tid >> 6;
  const int* mb = Mg + (size_t)b * S_N;
  int kept[8]; int cl = 0; int base = tid * 8;
  #pragma unroll
  for (int i = 0; i < 8; ++i){ kept[i] = (mb[base+i] == 0); cl += kept[i]; }
  int inc = cl;
  #pragma unroll
  for (int d = 1; d < 64; d <<= 1){
    int o = __shfl_up(inc, d);
    if (lane >= d) inc += o;
  }
  if (lane == 63) sws[w] = inc;
  __syncthreads();
  int s0 = sws[0], s1 = sws[1], s2 = sws[2], s3 = sws[3];
  int wo = (w > 0 ? s0 : 0) + (w > 1 ? s1 : 0) + (w > 2 ? s2 : 0);
  int pos = wo + inc - cl;
  #pragma unroll
  for (int i = 0; i < 8; ++i){
    if (kept[i]) idx_ws[b*S_N + pos++] = (ushort)(base + i);
  }
  if (tid == 0) cnt_ws[b] = s0 + s1 + s2 + s3;
}

// ---------------- pre-pass B: gather + convert + build images ----------------
// K image (per 64-key tile): rows jrow*128B, 16B granules XOR-swizzled by (jrow&7)
// (staged into LDS via global_load_lds).
// V^T image: GRANULE-TRANSPOSED (read direct from L2):
//   granule(g=0..3, h=0..1, d=0..63) at 16384 + g*2048 + h*1024 + d*16 (hi)
//   and +8192 for lo; elements e = V[h*32 + kap(g,e)][d],
//   kap(g,e) = g*4+(e&3)+16*(e>>2) -- matches MFMA C-layout so P is a bitcast.
__global__ __launch_bounds__(256)
void stage_k(const float* __restrict__ Kg, const float* __restrict__ Vg,
             const int* __restrict__ cnt_ws, const ushort* __restrict__ idx_ws,
             char* __restrict__ img)
{
  __shared__ float Vl[64*65];
  const int bid = blockIdx.x;
  const int bh = bid >> 5;
  const int tile = bid & 31;
  const int b = bh >> 4;
  const int cnt = cnt_ws[b];
  const int ntile = (cnt + 63) >> 6;
  if (tile >= ntile) return;
  const int tid = threadIdx.x;
  char* G = img + (size_t)bid * TILE_BYTES;

  const int jrow = tid >> 2, c4 = tid & 3;
  int kk = tile*64 + jrow; if (kk >= cnt) kk = cnt - 1;
  const int sidx = idx_ws[b*S_N + kk];
  const size_t kvbase = (size_t)bh * (size_t)(S_N*D_N);
  const int sw = (jrow & 7) << 4;
  {
    const float4* Kp = (const float4*)(Kg + kvbase + (size_t)sidx*D_N) + c4*4;
    float4 k0 = Kp[0], k1 = Kp[1], k2 = Kp[2], k3 = Kp[3];
    float kv[16] = {k0.x,k0.y,k0.z,k0.w,k1.x,k1.y,k1.z,k1.w,
                    k2.x,k2.y,k2.z,k2.w,k3.x,k3.y,k3.z,k3.w};
    uint h[16], l[16];
    #pragma unroll
    for (int e = 0; e < 16; ++e){
      uint hh = f2bf(kv[e]); h[e] = hh; l[e] = f2bf(kv[e] - bf2f(hh));
    }
    char* r0 = G + jrow*128;
    char* r1 = G + 8192 + jrow*128;
    *(u32x4a*)(r0 + ((c4*32)      ^ sw)) = (u32x4a){h[0]|(h[1]<<16),  h[2]|(h[3]<<16),
                                                    h[4]|(h[5]<<16),  h[6]|(h[7]<<16)};
    *(u32x4a*)(r0 + ((c4*32 + 16) ^ sw)) = (u32x4a){h[8]|(h[9]<<16),  h[10]|(h[11]<<16),
                                                    h[12]|(h[13]<<16),h[14]|(h[15]<<16)};
    *(u32x4a*)(r1 + ((c4*32)      ^ sw)) = (u32x4a){l[0]|(l[1]<<16),  l[2]|(l[3]<<16),
                                                    l[4]|(l[5]<<16),  l[6]|(l[7]<<16)};
    *(u32x4a*)(r1 + ((c4*32 + 16) ^ sw)) = (u32x4a){l[8]|(l[9]<<16),  l[10]|(l[11]<<16),
                                                    l[12]|(l[13]<<16),l[14]|(l[15]<<16)};
  }
  {
    const float4* Vp = (const float4*)(Vg + kvbase + (size_t)sidx*D_N) + c4*4;
    float4 v0 = Vp[0], v1 = Vp[1], v2 = Vp[2], v3 = Vp[3];
    float vv[16] = {v0.x,v0.y,v0.z,v0.w,v1.x,v1.y,v1.z,v1.w,
                    v2.x,v2.y,v2.z,v2.w,v3.x,v3.y,v3.z,v3.w};
    #pragma unroll
    for (int e = 0; e < 16; ++e) Vl[jrow*65 + c4*16 + e] = vv[e];
  }
  __syncthreads();
  // V^T granules with kap ordering, granule-transposed placement
  #pragma unroll
  for (int t = 0; t < 2; ++t){
    int idx2 = tid + t*256;
    int d = idx2 >> 3;
    int h = (idx2 >> 2) & 1;
    int g = idx2 & 3;
    int kb = h*32 + g*4;
    uint hh[8], ll[8];
    #pragma unroll
    for (int e = 0; e < 8; ++e){
      int k = kb + (e & 3) + ((e >> 2) << 4);   // kap(g,e) within half
      float x = Vl[k*65 + d];
      uint hv = f2bf(x); hh[e] = hv; ll[e] = f2bf(x - bf2f(hv));
    }
    *(u32x4a*)(G + 16384 + g*2048 + h*1024 + d*16) =
        (u32x4a){hh[0]|(hh[1]<<16), hh[2]|(hh[3]<<16), hh[4]|(hh[5]<<16), hh[6]|(hh[7]<<16)};
    *(u32x4a*)(G + 24576 + g*2048 + h*1024 + d*16) =
        (u32x4a){ll[0]|(ll[1]<<16), ll[2]|(ll[3]<<16), ll[4]|(ll[5]<<16), ll[6]|(ll[7]<<16)};
  }
}

// ---------------- main attention kernel: round-9 + EARLY V issue ----------------
// Identical bytes/order to round 9 (sentinel: absmax must stay 1.953125e-3).
// Only change: the 8 V global loads are issued at the TOP of the loop body
// (before K stage + QK^T) into registers, so L2 latency hides under the
// ~1000+cyc QK^T/softmax phase instead of stalling PV. V loads precede the
// stage gload_lds so waiting on V is vmcnt(4), not a queue drain.
__global__ __launch_bounds__(256, 2)
void attn10_k(const float* __restrict__ Qg, const char* __restrict__ img,
              const int* __restrict__ cnt_ws, float* __restrict__ Og)
{
  __shared__ __align__(16) char smem[2][8192];   // [buf][Khi 4KB | Klo 4KB]

  const int tid  = threadIdx.x;
  const int lane = tid & 63;
  const int w    = tid >> 6;
  const int c    = lane & 15;
  const int gi   = lane >> 4;

  int bid = blockIdx.x;
  int wg  = (bid & 7) * (NBLK/8) + (bid >> 3);
  int qt  = wg & 15;
  int bh  = wg >> 4;
  int b   = bh >> 4;

  const int cnt = cnt_ws[b];
  const int nhalf = (cnt + 31) >> 5;
  const char* Gb = img + (size_t)bh * MAXTILE * TILE_BYTES;

  // stage K half-tile hidx into buffer sb (waves 0,1 only)
  auto stage = [&](int hidx, int sb){
    if (w < 2){
      const char* T = Gb + (size_t)(hidx >> 1) * TILE_BYTES;
      const int h = hidx & 1;
      const char* src = T + w*8192 + h*4096 + lane*16;
      char* dst = (char*)&smem[sb][0] + w*4096;
      #pragma unroll
      for (int i = 0; i < 4; ++i) gload16(src + i*1024, dst + i*1024);
    }
  };

  if (nhalf > 0) stage(0, 0);

  // Q fragments hi/lo in registers (B-operand of swapped QK^T)
  const int q0w = qt * BQ + w * WQ;
  bf16x8 qh[2][2], ql[2][2];
  {
    const float* Qbase = Qg + (size_t)bh * S_N * D_N;
    #pragma unroll
    for (int qs = 0; qs < 2; ++qs){
      const float* qr = Qbase + (size_t)(q0w + qs*16 + c) * D_N;
      #pragma unroll
      for (int ks = 0; ks < 2; ++ks){
        const float4* p4 = (const float4*)(qr + ks*32 + gi*8);
        float4 x0 = p4[0], x1 = p4[1];
        float xs[8] = {x0.x,x0.y,x0.z,x0.w,x1.x,x1.y,x1.z,x1.w};
        union { bf16x8 v; ushort u[8]; } uh, ul;
        #pragma unroll
        for (int e = 0; e < 8; ++e){
          uint h = f2bf(xs[e]);
          uh.u[e] = (ushort)h;
          ul.u[e] = (ushort)f2bf(xs[e] - bf2f(h));
        }
        qh[qs][ks] = uh.v; ql[qs][ks] = ul.v;
      }
    }
  }

  f32x4 Oa[2][4];
  #pragma unroll
  for (int i = 0; i < 2; ++i)
    #pragma unroll
    for (int jj = 0; jj < 4; ++jj)
      Oa[i][jj] = (f32x4){0.f,0.f,0.f,0.f};
  float zz[2] = {0.f, 0.f};

  const int swc16 = (c & 7) << 4;
  const int e0 = (gi*16) ^ swc16;
  const int e1 = (64 + gi*16) ^ swc16;

  __syncthreads();

  for (int tb = 0; tb < nhalf; ++tb){
    const int buf = tb & 1;

    // ---- EARLY V issue: 8 global loads into registers, used in PV below ----
    const char* VB = Gb + (size_t)(tb >> 1) * TILE_BYTES + 16384
                     + gi*2048 + (tb & 1)*1024 + c*16;
    bf16x8 vhx[4], vlx[4];
    #pragma unroll
    for (int ds = 0; ds < 4; ++ds){
      vhx[ds] = *(const bf16x8*)(VB + ds*256);
      vlx[ds] = *(const bf16x8*)(VB + 8192 + ds*256);
    }

    if (tb + 1 < nhalf) stage(tb + 1, buf ^ 1);
    const char* Khi  = &smem[buf][0];
    const char* Klo  = Khi + 4096;
    const bool lastt = (tb == nhalf - 1);

    uint sH[2][4], sL[2][4];   // [qs][hA_kt0,hB_kt0,hA_kt1,hB_kt1]
    #pragma unroll
    for (int kt = 0; kt < 2; ++kt){
      int row = kt*16 + c;
      const char* krh = Khi + row*128;
      const char* krl = Klo + row*128;
      bf16x8 kh0 = *(const bf16x8*)(krh + e0);
      bf16x8 kh1 = *(const bf16x8*)(krh + e1);
      bf16x8 kl0 = *(const bf16x8*)(krl + e0);
      bf16x8 kl1 = *(const bf16x8*)(krl + e1);
      #pragma unroll
      for (int qs = 0; qs < 2; ++qs){
        f32x4 s = (f32x4){0.f,0.f,0.f,0.f};
        s = MFMA16(kh0, qh[qs][0], s, 0,0,0);
        s = MFMA16(kh1, qh[qs][1], s, 0,0,0);
        s = MFMA16(kh0, ql[qs][0], s, 0,0,0);
        s = MFMA16(kh1, ql[qs][1], s, 0,0,0);
        s = MFMA16(kl0, qh[qs][0], s, 0,0,0);
        s = MFMA16(kl1, qh[qs][1], s, 0,0,0);
        // p = exp(10*tanh(s/8) - 10) = exp2(-28.8539 / (exp2(s*0.360674)+1))
        float pv[4];
        #pragma unroll
        for (int r = 0; r < 4; ++r){
          float t  = __builtin_amdgcn_exp2f(s[r] * 0.3606737602222409f);
          float wv = __builtin_amdgcn_rcpf(t + 1.0f);
          pv[r] = __builtin_amdgcn_exp2f(-28.853900817779268f * wv);
        }
        if (lastt){
          int kg0 = tb*32 + kt*16 + gi*4;
          #pragma unroll
          for (int r = 0; r < 4; ++r) if (kg0 + r >= cnt) pv[r] = 0.f;
        }
        zz[qs] += (pv[0] + pv[1]) + (pv[2] + pv[3]);
        uint hA, hB, lA, lB;
        asm("v_cvt_pk_bf16_f32 %0, %1, %2" : "=v"(hA) : "v"(pv[0]), "v"(pv[1]));
        asm("v_cvt_pk_bf16_f32 %0, %1, %2" : "=v"(hB) : "v"(pv[2]), "v"(pv[3]));
        float l0 = pv[0] - __uint_as_float(hA << 16);
        float l1 = pv[1] - __uint_as_float(hA & 0xffff0000u);
        float l2 = pv[2] - __uint_as_float(hB << 16);
        float l3 = pv[3] - __uint_as_float(hB & 0xffff0000u);
        asm("v_cvt_pk_bf16_f32 %0, %1, %2" : "=v"(lA) : "v"(l0), "v"(l1));
        asm("v_cvt_pk_bf16_f32 %0, %1, %2" : "=v"(lB) : "v"(l2), "v"(l3));
        sH[qs][kt*2+0] = hA; sH[qs][kt*2+1] = hB;
        sL[qs][kt*2+0] = lA; sL[qs][kt*2+1] = lB;
      }
    }
    // P fragments: pure bitcast (k-order kap matches the V^T image)
    union PU { u32x4a g; bf16x8 v; };
    PU pah[2], pal[2];
    #pragma unroll
    for (int qs = 0; qs < 2; ++qs){
      pah[qs].g = (u32x4a){sH[qs][0], sH[qs][1], sH[qs][2], sH[qs][3]};
      pal[qs].g = (u32x4a){sL[qs][0], sL[qs][1], sL[qs][2], sL[qs][3]};
    }
    #pragma unroll
    for (int ds = 0; ds < 4; ++ds){
      #pragma unroll
      for (int qs = 0; qs < 2; ++qs){
        f32x4 o = Oa[qs][ds];
        o = MFMA16(pah[qs].v, vhx[ds], o, 0,0,0);
        o = MFMA16(pah[qs].v, vlx[ds], o, 0,0,0);
        o = MFMA16(pal[qs].v, vhx[ds], o, 0,0,0);
        Oa[qs][ds] = o;
      }
    }
    __syncthreads();
  }

  // ---------- epilogue ----------
  #pragma unroll
  for (int qs = 0; qs < 2; ++qs){
    float zt = zz[qs];
    zt += __shfl_xor(zt, 16);
    zt += __shfl_xor(zt, 32);
    float rz = 1.0f / zt;
    #pragma unroll
    for (int r = 0; r < 4; ++r){
      float rzq = __shfl(rz, gi*4 + r);
      size_t rowbase = ((size_t)bh * S_N + (size_t)(q0w + qs*16 + gi*4 + r)) * D_N;
      #pragma unroll
      for (int ds = 0; ds < 4; ++ds){
        Og[rowbase + ds*16 + c] = Oa[qs][ds][r] * rzq;
      }
    }
  }
}

// ---------------- fallback (round-1 kernel, self-staging) ----------------
__global__ __launch_bounds__(256, 2)
void attn_k(const float* __restrict__ Qg, const float* __restrict__ Kg,
            const float* __restrict__ Vg, const int* __restrict__ Mg,
            float* __restrict__ Og)
{
  __shared__ __align__(16) ushort Khi[KT*D_N];
  __shared__ __align__(16) ushort Klo[KT*D_N];
  __shared__ __align__(16) ushort Vhi[D_N*72];
  __shared__ __align__(16) ushort Vlo[D_N*72];
  __shared__ __align__(16) ushort Phl[NW*16*72];
  __shared__ __align__(16) ushort Pll[NW*16*72];
  __shared__ ushort idx_l[S_N];
  __shared__ int scan_ws[NW];

  const int tid  = threadIdx.x;
  const int lane = tid & 63;
  const int w    = tid >> 6;
  const int c    = lane & 15;
  const int gi   = lane >> 4;

  int bid = blockIdx.x;
  int wg  = (bid & 7) * (NBLK/8) + (bid >> 3);
  int qt  = wg & 15;
  int bh  = wg >> 4;
  int b   = bh >> 4;

  int cnt;
  {
    const int* mb = Mg + (size_t)b * S_N;
    int kept[8]; int cl = 0;
    int base = tid * 8;
    #pragma unroll
    for (int i = 0; i < 8; ++i){ kept[i] = (mb[base+i] == 0); cl += kept[i]; }
    int inc = cl;
    #pragma unroll
    for (int d = 1; d < 64; d <<= 1){
      int o = __shfl_up(inc, d);
      if (lane >= d) inc += o;
    }
    if (lane == 63) scan_ws[w] = inc;
    __syncthreads();
    int s0 = scan_ws[0], s1 = scan_ws[1], s2 = scan_ws[2], s3 = scan_ws[3];
    int wo = (w > 0 ? s0 : 0) + (w > 1 ? s1 : 0) + (w > 2 ? s2 : 0);
    cnt = s0 + s1 + s2 + s3;
    int pos = wo + inc - cl;
    #pragma unroll
    for (int i = 0; i < 8; ++i){
      if (kept[i]) idx_l[pos++] = (ushort)(base + i);
    }
    __syncthreads();
  }

  const int q0w = qt * BQ + w * WQ;
  bf16x8 qh[2][2], ql[2][2];
  {
    const float* Qbase = Qg + (size_t)bh * S_N * D_N;
    #pragma unroll
    for (int qs = 0; qs < 2; ++qs){
      const float* qr = Qbase + (size_t)(q0w + qs*16 + c) * D_N;
      #pragma unroll
      for (int ks = 0; ks < 2; ++ks){
        const float4* p4 = (const float4*)(qr + ks*32 + gi*8);
        float4 x0 = p4[0], x1 = p4[1];
        float xs[8] = {x0.x,x0.y,x0.z,x0.w,x1.x,x1.y,x1.z,x1.w};
        union { bf16x8 v; ushort u[8]; } uh, ul;
        #pragma unroll
        for (int e = 0; e < 8; ++e){
          uint h = f2bf(xs[e]);
          uh.u[e] = (ushort)h;
          ul.u[e] = (ushort)f2bf(xs[e] - bf2f(h));
        }
        qh[qs][ks] = uh.v; ql[qs][ks] = ul.v;
      }
    }
  }

  f32x4 Oa[2][4];
  #pragma unroll
  for (int i = 0; i < 2; ++i)
    #pragma unroll
    for (int jj = 0; jj < 4; ++jj)
      Oa[i][jj] = (f32x4){0.f,0.f,0.f,0.f};
  float zz[2] = {0.f, 0.f};

  ushort* Ph = Phl + w * (16*72);
  ushort* Pl = Pll + w * (16*72);

  const int jrow = tid >> 2;
  const int c4   = tid & 3;
  const size_t kvbase = (size_t)bh * S_N * D_N;

  const int ntile = (cnt + KT - 1) >> 6;
  for (int tb = 0; tb < ntile; ++tb){
    {
      int kk = tb*KT + jrow;
      int ci = kk < cnt ? kk : cnt - 1;
      int sidx = idx_l[ci];
      const float4* Kp = (const float4*)(Kg + kvbase + (size_t)sidx * D_N) + c4*4;
      const float4* Vp = (const float4*)(Vg + kvbase + (size_t)sidx * D_N) + c4*4;
      float4 k0 = Kp[0], k1 = Kp[1], k2 = Kp[2], k3 = Kp[3];
      float kv[16] = {k0.x,k0.y,k0.z,k0.w,k1.x,k1.y,k1.z,k1.w,
                      k2.x,k2.y,k2.z,k2.w,k3.x,k3.y,k3.z,k3.w};
      uint kh[16], klv[16];
      #pragma unroll
      for (int e = 0; e < 16; ++e){
        uint h = f2bf(kv[e]);
        kh[e] = h; klv[e] = f2bf(kv[e] - bf2f(h));
      }
      u32x4a H0 = (u32x4a){kh[0]|(kh[1]<<16),   kh[2]|(kh[3]<<16),
                           kh[4]|(kh[5]<<16),   kh[6]|(kh[7]<<16)};
      u32x4a H1 = (u32x4a){kh[8]|(kh[9]<<16),   kh[10]|(kh[11]<<16),
                           kh[12]|(kh[13]<<16), kh[14]|(kh[15]<<16)};
      u32x4a L0 = (u32x4a){klv[0]|(klv[1]<<16),   klv[2]|(klv[3]<<16),
                           klv[4]|(klv[5]<<16),   klv[6]|(klv[7]<<16)};
      u32x4a L1 = (u32x4a){klv[8]|(klv[9]<<16),   klv[10]|(klv[11]<<16),
                           klv[12]|(klv[13]<<16), klv[14]|(klv[15]<<16)};
      char* krh = (char*)Khi + jrow*128;
      char* krl = (char*)Klo + jrow*128;
      int o0 = ldsw(c4*32, jrow), o1 = ldsw(c4*32 + 16, jrow);
      *(u32x4a*)(krh + o0) = H0;  *(u32x4a*)(krh + o1) = H1;
      *(u32x4a*)(krl + o0) = L0;  *(u32x4a*)(krl + o1) = L1;

      float4 v0 = Vp[0], v1 = Vp[1], v2 = Vp[2], v3 = Vp[3];
      float vv[16] = {v0.x,v0.y,v0.z,v0.w,v1.x,v1.y,v1.z,v1.w,
                      v2.x,v2.y,v2.z,v2.w,v3.x,v3.y,v3.z,v3.w};
      #pragma unroll
      for (int e = 0; e < 16; ++e){
        int d = c4*16 + e;
        uint h  = f2bf(vv[e]);
        uint l2 = f2bf(vv[e] - bf2f(h));
        int off = d*144 + ldsw(jrow*2, d);
        *(ushort*)((char*)Vhi + off) = (ushort)h;
        *(ushort*)((char*)Vlo + off) = (ushort)l2;
      }
    }
    __syncthreads();

    const bool lastt = (tb == ntile - 1);
    #pragma unroll
    for (int qs = 0; qs < 2; ++qs){
      #pragma unroll
      for (int kt = 0; kt < 4; ++kt){
        int row = kt*16 + c;
        const char* krh = (const char*)Khi + row*128;
        const char* krl = (const char*)Klo + row*128;
        int e0 = ldsw(16*gi, row), e1 = ldsw(64 + 16*gi, row);
        bf16x8 kh0 = *(const bf16x8*)(krh + e0);
        bf16x8 kh1 = *(const bf16x8*)(krh + e1);
        bf16x8 kl0 = *(const bf16x8*)(krl + e0);
        bf16x8 kl1 = *(const bf16x8*)(krl + e1);
        f32x4 s = (f32x4){0.f,0.f,0.f,0.f};
        s = MFMA16(kh0, qh[qs][0], s, 0,0,0);
        s = MFMA16(kh1, qh[qs][1], s, 0,0,0);
        s = MFMA16(kh0, ql[qs][0], s, 0,0,0);
        s = MFMA16(kh1, ql[qs][1], s, 0,0,0);
        s = MFMA16(kl0, qh[qs][0], s, 0,0,0);
        s = MFMA16(kl1, qh[qs][1], s, 0,0,0);
        float pv[4];
        #pragma unroll
        for (int r = 0; r < 4; ++r){
          float t  = __builtin_amdgcn_exp2f(s[r] * 0.3606737602222409f);
          float wv = __builtin_amdgcn_rcpf(t + 1.0f);
          pv[r] = __builtin_amdgcn_exp2f(-28.853900817779268f * wv);
        }
        if (lastt){
          int kg0 = tb*KT + kt*16 + gi*4;
          #pragma unroll
          for (int r = 0; r < 4; ++r) if (kg0 + r >= cnt) pv[r] = 0.f;
        }
        zz[qs] += (pv[0] + pv[1]) + (pv[2] + pv[3]);
        uint h0 = f2bf(pv[0]), h1 = f2bf(pv[1]),
             h2 = f2bf(pv[2]), h3 = f2bf(pv[3]);
        uint l0 = f2bf(pv[0]-bf2f(h0)), l1 = f2bf(pv[1]-bf2f(h1)),
             l2 = f2bf(pv[2]-bf2f(h2)), l3 = f2bf(pv[3]-bf2f(h3));
        int ow = c*144 + ldsw(kt*32 + gi*8, c);
        *(u32x2a*)((char*)Ph + ow) = (u32x2a){h0|(h1<<16), h2|(h3<<16)};
        *(u32x2a*)((char*)Pl + ow) = (u32x2a){l0|(l1<<16), l2|(l3<<16)};
      }
      bf16x8 pah[2], pal[2];
      {
        const char* prh = (const char*)Ph + c*144;
        const char* prl = (const char*)Pl + c*144;
        #pragma unroll
        for (int ks = 0; ks < 2; ++ks){
          int oo = ldsw(64*ks + 16*gi, c);
          pah[ks] = *(const bf16x8*)(prh + oo);
          pal[ks] = *(const bf16x8*)(prl + oo);
        }
      }
      #pragma unroll
      for (int ds = 0; ds < 4; ++ds){
        int drow = ds*16 + c;
        const char* vrh = (const char*)Vhi + drow*144;
        const char* vrl = (const char*)Vlo + drow*144;
        f32x4 o = Oa[qs][ds];
        #pragma unroll
        for (int ks = 0; ks < 2; ++ks){
          int oo = ldsw(64*ks + 16*gi, drow);
          bf16x8 vh = *(const bf16x8*)(vrh + oo);
          bf16x8 vl = *(const bf16x8*)(vrl + oo);
          o = MFMA16(pah[ks], vh, o, 0,0,0);
          o = MFMA16(pah[ks], vl, o, 0,0,0);
          o = MFMA16(pal[ks], vh, o, 0,0,0);
        }
        Oa[qs][ds] = o;
      }
    }
    __syncthreads();
  }

  #pragma unroll
  for (int qs = 0; qs < 2; ++qs){
    float zt = zz[qs];
    zt += __shfl_xor(zt, 16);
    zt += __shfl_xor(zt, 32);
    float rz = 1.0f / zt;
    #pragma unroll
    for (int r = 0; r < 4; ++r){
      float rzq = __shfl(rz, gi*4 + r);
      size_t rowbase = ((size_t)bh * S_N + (size_t)(q0w + qs*16 + gi*4 + r)) * D_N;
      #pragma unroll
      for (int ds = 0; ds < 4; ++ds){
        Og[rowbase + ds*16 + c] = Oa[qs][ds][r] * rzq;
      }
    }
  }
}

extern "C" void kernel_launch(void* const* d_in, const int* in_sizes, int n_in,
                              void* d_out, int out_size, void* d_ws, size_t ws_size,
                              hipStream_t stream) {
  const float* Qg = (const float*)d_in[0];
  const float* Kg = (const float*)d_in[1];
  const float* Vg = (const float*)d_in[2];
  const int*   Mg = (const int*)d_in[3];
  float* Og = (float*)d_out;
  if (ws_size >= WS_NEED){
    int*    cnt_ws = (int*)d_ws;
    ushort* idx_ws = (ushort*)((char*)d_ws + 64);
    char*   img    = (char*)d_ws + IMG_OFF;
    compact_k<<<dim3(B_N), dim3(256), 0, stream>>>(Mg, cnt_ws, idx_ws);
    stage_k<<<dim3(B_N*H_N*MAXTILE), dim3(256), 0, stream>>>(Kg, Vg, cnt_ws, idx_ws, img);
    attn10_k<<<dim3(NBLK), dim3(256), 0, stream>>>(Qg, img, cnt_ws, Og);
  } else {
    attn_k<<<dim3(NBLK), dim3(256), 0, stream>>>(Qg, Kg, Vg, Mg, Og);
  }
}

// Round 13
// 133.705 us; speedup vs baseline: 1.2532x; 1.0886x over previous
//
#include <hip/hip_runtime.h>

typedef short bf16x8 __attribute__((ext_vector_type(8), may_alias));
typedef float f32x4 __attribute__((ext_vector_type(4)));
typedef unsigned int u32x4a __attribute__((ext_vector_type(4), may_alias));
typedef unsigned int u32x2a __attribute__((ext_vector_type(2), may_alias));
typedef unsigned short ushort;
typedef unsigned int uint;

#define B_N 4
#define H_N 16
#define S_N 2048
#define D_N 64
#define BQ 128      // q rows per block
#define WQ 32       // q rows per wave
#define KT 64       // key tile in the image / fallback kernel
#define NW 4        // waves per block
#define NBLK (B_N*H_N*(S_N/BQ))   // 1024 blocks
#define TILE_BYTES 32768          // image tile: Khi|Klo|VThi|VTlo, 8KB each (64 keys)
#define MAXTILE (S_N/KT)          // 32
#define IMG_OFF 32768
#define WS_NEED ((size_t)IMG_OFF + (size_t)B_N*H_N*MAXTILE*TILE_BYTES)

#define MFMA16 __builtin_amdgcn_mfma_f32_16x16x32_bf16

// f32 -> bf16 round-to-nearest-even (bit trick)
__device__ __forceinline__ uint f2bf(float x){
  uint u = __float_as_uint(x);
  u += 0x7fffu + ((u >> 16) & 1u);
  return u >> 16;
}
__device__ __forceinline__ float bf2f(uint h){
  return __uint_as_float(h << 16);
}
__device__ __forceinline__ int ldsw(int off, int row){
  return off ^ ((row & 7) << 4);
}
__device__ __forceinline__ void gload16(const void* g, void* l){
  __builtin_amdgcn_global_load_lds((const uint __attribute__((address_space(1)))*)g,
                                   (uint __attribute__((address_space(3)))*)l, 16, 0, 0);
}

// ---------------- pre-pass A: per-b mask compaction ----------------
__global__ __launch_bounds__(256)
void compact_k(const int* __restrict__ Mg, int* __restrict__ cnt_ws,
               ushort* __restrict__ idx_ws)
{
  __shared__ int sws[NW];
  const int b = blockIdx.x;
  const int tid = threadIdx.x, lane = tid & 63, w = tid >> 6;
  const int* mb = Mg + (size_t)b * S_N;
  int kept[8]; int cl = 0; int base = tid * 8;
  #pragma unroll
  for (int i = 0; i < 8; ++i){ kept[i] = (mb[base+i] == 0); cl += kept[i]; }
  int inc = cl;
  #pragma unroll
  for (int d = 1; d < 64; d <<= 1){
    int o = __shfl_up(inc, d);
    if (lane >= d) inc += o;
  }
  if (lane == 63) sws[w] = inc;
  __syncthreads();
  int s0 = sws[0], s1 = sws[1], s2 = sws[2], s3 = sws[3];
  int wo = (w > 0 ? s0 : 0) + (w > 1 ? s1 : 0) + (w > 2 ? s2 : 0);
  int pos = wo + inc - cl;
  #pragma unroll
  for (int i = 0; i < 8; ++i){
    if (kept[i]) idx_ws[b*S_N + pos++] = (ushort)(base + i);
  }
  if (tid == 0) cnt_ws[b] = s0 + s1 + s2 + s3;
}

// ---------------- pre-pass B: gather + convert + build LDS images ----------------
// K image (per 64-key tile): rows jrow*128B, 16B granules XOR-swizzled by (jrow&7).
// V^T image: row d = 128B = [half0 64B | half1 64B]; 16B chunk g of half h holds
// elements e = V[h*32 + kap(g,e)][d], kap(g,e) = g*4+(e&3) + 16*(e>>2).
// kap matches the MFMA C-layout key positions so P needs NO redistribution.
__global__ __launch_bounds__(256)
void stage_k(const float* __restrict__ Kg, const float* __restrict__ Vg,
             const int* __restrict__ cnt_ws, const ushort* __restrict__ idx_ws,
             char* __restrict__ img)
{
  __shared__ float Vl[64*65];
  const int bid = blockIdx.x;
  const int bh = bid >> 5;
  const int tile = bid & 31;
  const int b = bh >> 4;
  const int cnt = cnt_ws[b];
  const int ntile = (cnt + 63) >> 6;
  if (tile >= ntile) return;
  const int tid = threadIdx.x;
  char* G = img + (size_t)bid * TILE_BYTES;

  const int jrow = tid >> 2, c4 = tid & 3;
  int kk = tile*64 + jrow; if (kk >= cnt) kk = cnt - 1;
  const int sidx = idx_ws[b*S_N + kk];
  const size_t kvbase = (size_t)bh * (size_t)(S_N*D_N);
  const int sw = (jrow & 7) << 4;
  {
    const float4* Kp = (const float4*)(Kg + kvbase + (size_t)sidx*D_N) + c4*4;
    float4 k0 = Kp[0], k1 = Kp[1], k2 = Kp[2], k3 = Kp[3];
    float kv[16] = {k0.x,k0.y,k0.z,k0.w,k1.x,k1.y,k1.z,k1.w,
                    k2.x,k2.y,k2.z,k2.w,k3.x,k3.y,k3.z,k3.w};
    uint h[16], l[16];
    #pragma unroll
    for (int e = 0; e < 16; ++e){
      uint hh = f2bf(kv[e]); h[e] = hh; l[e] = f2bf(kv[e] - bf2f(hh));
    }
    char* r0 = G + jrow*128;
    char* r1 = G + 8192 + jrow*128;
    *(u32x4a*)(r0 + ((c4*32)      ^ sw)) = (u32x4a){h[0]|(h[1]<<16),  h[2]|(h[3]<<16),
                                                    h[4]|(h[5]<<16),  h[6]|(h[7]<<16)};
    *(u32x4a*)(r0 + ((c4*32 + 16) ^ sw)) = (u32x4a){h[8]|(h[9]<<16),  h[10]|(h[11]<<16),
                                                    h[12]|(h[13]<<16),h[14]|(h[15]<<16)};
    *(u32x4a*)(r1 + ((c4*32)      ^ sw)) = (u32x4a){l[0]|(l[1]<<16),  l[2]|(l[3]<<16),
                                                    l[4]|(l[5]<<16),  l[6]|(l[7]<<16)};
    *(u32x4a*)(r1 + ((c4*32 + 16) ^ sw)) = (u32x4a){l[8]|(l[9]<<16),  l[10]|(l[11]<<16),
                                                    l[12]|(l[13]<<16),l[14]|(l[15]<<16)};
  }
  {
    const float4* Vp = (const float4*)(Vg + kvbase + (size_t)sidx*D_N) + c4*4;
    float4 v0 = Vp[0], v1 = Vp[1], v2 = Vp[2], v3 = Vp[3];
    float vv[16] = {v0.x,v0.y,v0.z,v0.w,v1.x,v1.y,v1.z,v1.w,
                    v2.x,v2.y,v2.z,v2.w,v3.x,v3.y,v3.z,v3.w};
    #pragma unroll
    for (int e = 0; e < 16; ++e) Vl[jrow*65 + c4*16 + e] = vv[e];
  }
  __syncthreads();
  // V^T image with kap ordering: 512 granules (d 0..63, h 0..1, g 0..3)
  #pragma unroll
  for (int t = 0; t < 2; ++t){
    int idx2 = tid + t*256;
    int d = idx2 >> 3;
    int h = (idx2 >> 2) & 1;
    int g = idx2 & 3;
    int kb = h*32 + g*4;
    uint hh[8], ll[8];
    #pragma unroll
    for (int e = 0; e < 8; ++e){
      int k = kb + (e & 3) + ((e >> 2) << 4);   // kap(g,e) within half
      float x = Vl[k*65 + d];
      uint hv = f2bf(x); hh[e] = hv; ll[e] = f2bf(x - bf2f(hv));
    }
    *(u32x4a*)(G + 16384 + d*128 + h*64 + g*16) =
        (u32x4a){hh[0]|(hh[1]<<16), hh[2]|(hh[3]<<16), hh[4]|(hh[5]<<16), hh[6]|(hh[7]<<16)};
    *(u32x4a*)(G + 24576 + d*128 + h*64 + g*16) =
        (u32x4a){ll[0]|(ll[1]<<16), ll[2]|(ll[3]<<16), ll[4]|(ll[5]<<16), ll[6]|(ll[7]<<16)};
  }
}

// ---------------- main attention kernel: r5 math, full 64-key tiles ----------------
// Bit-identical arithmetic and accumulation order vs round 5 (sentinel: absmax
// must equal 1.953125e-3). Structural changes only:
//  - full 64-key tile per iteration -> 32 barriers instead of 64 (halves the
//    per-barrier vmcnt/lgkmcnt drain cost)
//  - V^T staged as 128B LDS rows, XOR-swizzled via pre-swizzled gload_lds
//    SOURCE (linear dest + swizzled read, both-sides rule): kills the V-path
//    bank conflicts (was all 4.26e6 of r5's count, per r9's zero-conflict K-only run)
// __launch_bounds__(256,2) kept: (256,4) is confirmed poison (r3/r11).
__global__ __launch_bounds__(256, 2)
void attn13_k(const float* __restrict__ Qg, const char* __restrict__ img,
              const int* __restrict__ cnt_ws, float* __restrict__ Og)
{
  __shared__ __align__(16) char smem[2][32768];  // [buf][Khi 8K|Klo 8K|VThi 8K|VTlo 8K]

  const int tid  = threadIdx.x;
  const int lane = tid & 63;
  const int w    = tid >> 6;
  const int c    = lane & 15;
  const int gi   = lane >> 4;

  int bid = blockIdx.x;
  int wg  = (bid & 7) * (NBLK/8) + (bid >> 3);
  int qt  = wg & 15;
  int bh  = wg >> 4;
  int b   = bh >> 4;

  const int cnt = cnt_ws[b];
  const int ntile = (cnt + 63) >> 6;
  const char* Gb = img + (size_t)bh * MAXTILE * TILE_BYTES;

  // stage full tile t into buffer sb: per-lane SOURCE addr, wave-uniform LDS dest
  auto stage = [&](int t, int sb){
    const char* T = Gb + (size_t)t * TILE_BYTES;
    char* Bse = (char*)&smem[sb][0];
    if (w < 2){
      // K hi (w=0) / lo (w=1): linear 8KB copy
      const char* src = T + w*8192 + lane*16;
      char* dst = Bse + w*8192;
      #pragma unroll
      for (int i = 0; i < 8; ++i) gload16(src + i*1024, dst + i*1024);
    } else {
      // V^T hi (w=2) / lo (w=3): linear dest; source pre-swizzled so that
      // lds[d*128 + off] = img[d*128 + (off ^ ((d&7)<<4))]
      const int hl = w - 2;
      const char* base = T + 16384 + hl*8192;
      char* dst = Bse + 16384 + hl*8192;
      #pragma unroll
      for (int i = 0; i < 8; ++i){
        int pos = i*1024 + lane*16;
        int d = pos >> 7;
        int off = pos & 127;
        gload16(base + d*128 + (off ^ ((d & 7) << 4)), dst + i*1024);
      }
    }
  };

  if (ntile > 0) stage(0, 0);

  // Q fragments hi/lo in registers (B-operand of swapped QK^T)
  const int q0w = qt * BQ + w * WQ;
  bf16x8 qh[2][2], ql[2][2];
  {
    const float* Qbase = Qg + (size_t)bh * S_N * D_N;
    #pragma unroll
    for (int qs = 0; qs < 2; ++qs){
      const float* qr = Qbase + (size_t)(q0w + qs*16 + c) * D_N;
      #pragma unroll
      for (int ks = 0; ks < 2; ++ks){
        const float4* p4 = (const float4*)(qr + ks*32 + gi*8);
        float4 x0 = p4[0], x1 = p4[1];
        float xs[8] = {x0.x,x0.y,x0.z,x0.w,x1.x,x1.y,x1.z,x1.w};
        union { bf16x8 v; ushort u[8]; } uh, ul;
        #pragma unroll
        for (int e = 0; e < 8; ++e){
          uint h = f2bf(xs[e]);
          uh.u[e] = (ushort)h;
          ul.u[e] = (ushort)f2bf(xs[e] - bf2f(h));
        }
        qh[qs][ks] = uh.v; ql[qs][ks] = ul.v;
      }
    }
  }

  f32x4 Oa[2][4];
  #pragma unroll
  for (int i = 0; i < 2; ++i)
    #pragma unroll
    for (int jj = 0; jj < 4; ++jj)
      Oa[i][jj] = (f32x4){0.f,0.f,0.f,0.f};
  float zz[2] = {0.f, 0.f};

  const int swc16 = (c & 7) << 4;
  const int e0 = (gi*16) ^ swc16;
  const int e1 = (64 + gi*16) ^ swc16;

  __syncthreads();

  for (int tb = 0; tb < ntile; ++tb){
    const int buf = tb & 1;
    if (tb + 1 < ntile) stage(tb + 1, buf ^ 1);
    const char* Khi  = &smem[buf][0];
    const char* Klo  = Khi + 8192;
    const char* VThi = Khi + 16384;
    const char* VTlo = Khi + 24576;
    const bool lastt = (tb == ntile - 1);

    uint sH[2][8], sL[2][8];   // [qs][kt*2 + word]
    #pragma unroll
    for (int kt = 0; kt < 4; ++kt){
      int row = kt*16 + c;
      const char* krh = Khi + row*128;
      const char* krl = Klo + row*128;
      bf16x8 kh0 = *(const bf16x8*)(krh + e0);
      bf16x8 kh1 = *(const bf16x8*)(krh + e1);
      bf16x8 kl0 = *(const bf16x8*)(krl + e0);
      bf16x8 kl1 = *(const bf16x8*)(krl + e1);
      #pragma unroll
      for (int qs = 0; qs < 2; ++qs){
        f32x4 s = (f32x4){0.f,0.f,0.f,0.f};
        s = MFMA16(kh0, qh[qs][0], s, 0,0,0);
        s = MFMA16(kh1, qh[qs][1], s, 0,0,0);
        s = MFMA16(kh0, ql[qs][0], s, 0,0,0);
        s = MFMA16(kh1, ql[qs][1], s, 0,0,0);
        s = MFMA16(kl0, qh[qs][0], s, 0,0,0);
        s = MFMA16(kl1, qh[qs][1], s, 0,0,0);
        // p = exp(10*tanh(s/8) - 10) = exp2(-28.8539 / (exp2(s*0.360674)+1))
        float pv[4];
        #pragma unroll
        for (int r = 0; r < 4; ++r){
          float t  = __builtin_amdgcn_exp2f(s[r] * 0.3606737602222409f);
          float wv = __builtin_amdgcn_rcpf(t + 1.0f);
          pv[r] = __builtin_amdgcn_exp2f(-28.853900817779268f * wv);
        }
        if (lastt){
          int kg0 = tb*64 + kt*16 + gi*4;
          #pragma unroll
          for (int r = 0; r < 4; ++r) if (kg0 + r >= cnt) pv[r] = 0.f;
        }
        zz[qs] += (pv[0] + pv[1]) + (pv[2] + pv[3]);
        uint hA, hB, lA, lB;
        asm("v_cvt_pk_bf16_f32 %0, %1, %2" : "=v"(hA) : "v"(pv[0]), "v"(pv[1]));
        asm("v_cvt_pk_bf16_f32 %0, %1, %2" : "=v"(hB) : "v"(pv[2]), "v"(pv[3]));
        float l0 = pv[0] - __uint_as_float(hA << 16);
        float l1 = pv[1] - __uint_as_float(hA & 0xffff0000u);
        float l2 = pv[2] - __uint_as_float(hB << 16);
        float l3 = pv[3] - __uint_as_float(hB & 0xffff0000u);
        asm("v_cvt_pk_bf16_f32 %0, %1, %2" : "=v"(lA) : "v"(l0), "v"(l1));
        asm("v_cvt_pk_bf16_f32 %0, %1, %2" : "=v"(lB) : "v"(l2), "v"(l3));
        sH[qs][kt*2+0] = hA; sH[qs][kt*2+1] = hB;
        sL[qs][kt*2+0] = lA; sL[qs][kt*2+1] = lB;
      }
    }
    // P fragments: pure bitcast (k-order kap matches the V^T image); half h
    // covers keys h*32..h*32+31 = kt 2h,2h+1 -> words sH[qs][4h..4h+3]
    union PU { u32x4a g; bf16x8 v; };
    PU pah[2][2], pal[2][2];
    #pragma unroll
    for (int qs = 0; qs < 2; ++qs){
      #pragma unroll
      for (int h = 0; h < 2; ++h){
        pah[qs][h].g = (u32x4a){sH[qs][4*h+0], sH[qs][4*h+1], sH[qs][4*h+2], sH[qs][4*h+3]};
        pal[qs][h].g = (u32x4a){sL[qs][4*h+0], sL[qs][4*h+1], sL[qs][4*h+2], sL[qs][4*h+3]};
      }
    }
    #pragma unroll
    for (int ds = 0; ds < 4; ++ds){
      int drow = ds*16 + c;
      const char* vbh = VThi + drow*128;
      const char* vbl = VTlo + drow*128;
      #pragma unroll
      for (int h = 0; h < 2; ++h){
        int vo = (h*64 + gi*16) ^ swc16;   // drow&7 == c&7
        bf16x8 vh = *(const bf16x8*)(vbh + vo);
        bf16x8 vl = *(const bf16x8*)(vbl + vo);
        #pragma unroll
        for (int qs = 0; qs < 2; ++qs){
          f32x4 o = Oa[qs][ds];
          o = MFMA16(pah[qs][h].v, vh, o, 0,0,0);
          o = MFMA16(pah[qs][h].v, vl, o, 0,0,0);
          o = MFMA16(pal[qs][h].v, vh, o, 0,0,0);
          Oa[qs][ds] = o;
        }
      }
    }
    __syncthreads();
  }

  // ---------- epilogue ----------
  #pragma unroll
  for (int qs = 0; qs < 2; ++qs){
    float zt = zz[qs];
    zt += __shfl_xor(zt, 16);
    zt += __shfl_xor(zt, 32);
    float rz = 1.0f / zt;
    #pragma unroll
    for (int r = 0; r < 4; ++r){
      float rzq = __shfl(rz, gi*4 + r);
      size_t rowbase = ((size_t)bh * S_N + (size_t)(q0w + qs*16 + gi*4 + r)) * D_N;
      #pragma unroll
      for (int ds = 0; ds < 4; ++ds){
        Og[rowbase + ds*16 + c] = Oa[qs][ds][r] * rzq;
      }
    }
  }
}

// ---------------- fallback (round-1 kernel, self-staging) ----------------
__global__ __launch_bounds__(256, 2)
void attn_k(const float* __restrict__ Qg, const float* __restrict__ Kg,
            const float* __restrict__ Vg, const int* __restrict__ Mg,
            float* __restrict__ Og)
{
  __shared__ __align__(16) ushort Khi[KT*D_N];
  __shared__ __align__(16) ushort Klo[KT*D_N];
  __shared__ __align__(16) ushort Vhi[D_N*72];
  __shared__ __align__(16) ushort Vlo[D_N*72];
  __shared__ __align__(16) ushort Phl[NW*16*72];
  __shared__ __align__(16) ushort Pll[NW*16*72];
  __shared__ ushort idx_l[S_N];
  __shared__ int scan_ws[NW];

  const int tid  = threadIdx.x;
  const int lane = tid & 63;
  const int w    = tid >> 6;
  const int c    = lane & 15;
  const int gi   = lane >> 4;

  int bid = blockIdx.x;
  int wg  = (bid & 7) * (NBLK/8) + (bid >> 3);
  int qt  = wg & 15;
  int bh  = wg >> 4;
  int b   = bh >> 4;

  int cnt;
  {
    const int* mb = Mg + (size_t)b * S_N;
    int kept[8]; int cl = 0;
    int base = tid * 8;
    #pragma unroll
    for (int i = 0; i < 8; ++i){ kept[i] = (mb[base+i] == 0); cl += kept[i]; }
    int inc = cl;
    #pragma unroll
    for (int d = 1; d < 64; d <<= 1){
      int o = __shfl_up(inc, d);
      if (lane >= d) inc += o;
    }
    if (lane == 63) scan_ws[w] = inc;
    __syncthreads();
    int s0 = scan_ws[0], s1 = scan_ws[1], s2 = scan_ws[2], s3 = scan_ws[3];
    int wo = (w > 0 ? s0 : 0) + (w > 1 ? s1 : 0) + (w > 2 ? s2 : 0);
    cnt = s0 + s1 + s2 + s3;
    int pos = wo + inc - cl;
    #pragma unroll
    for (int i = 0; i < 8; ++i){
      if (kept[i]) idx_l[pos++] = (ushort)(base + i);
    }
    __syncthreads();
  }

  const int q0w = qt * BQ + w * WQ;
  bf16x8 qh[2][2], ql[2][2];
  {
    const float* Qbase = Qg + (size_t)bh * S_N * D_N;
    #pragma unroll
    for (int qs = 0; qs < 2; ++qs){
      const float* qr = Qbase + (size_t)(q0w + qs*16 + c) * D_N;
      #pragma unroll
      for (int ks = 0; ks < 2; ++ks){
        const float4* p4 = (const float4*)(qr + ks*32 + gi*8);
        float4 x0 = p4[0], x1 = p4[1];
        float xs[8] = {x0.x,x0.y,x0.z,x0.w,x1.x,x1.y,x1.z,x1.w};
        union { bf16x8 v; ushort u[8]; } uh, ul;
        #pragma unroll
        for (int e = 0; e < 8; ++e){
          uint h = f2bf(xs[e]);
          uh.u[e] = (ushort)h;
          ul.u[e] = (ushort)f2bf(xs[e] - bf2f(h));
        }
        qh[qs][ks] = uh.v; ql[qs][ks] = ul.v;
      }
    }
  }

  f32x4 Oa[2][4];
  #pragma unroll
  for (int i = 0; i < 2; ++i)
    #pragma unroll
    for (int jj = 0; jj < 4; ++jj)
      Oa[i][jj] = (f32x4){0.f,0.f,0.f,0.f};
  float zz[2] = {0.f, 0.f};

  ushort* Ph = Phl + w * (16*72);
  ushort* Pl = Pll + w * (16*72);

  const int jrow = tid >> 2;
  const int c4   = tid & 3;
  const size_t kvbase = (size_t)bh * S_N * D_N;

  const int ntile = (cnt + KT - 1) >> 6;
  for (int tb = 0; tb < ntile; ++tb){
    {
      int kk = tb*KT + jrow;
      int ci = kk < cnt ? kk : cnt - 1;
      int sidx = idx_l[ci];
      const float4* Kp = (const float4*)(Kg + kvbase + (size_t)sidx * D_N) + c4*4;
      const float4* Vp = (const float4*)(Vg + kvbase + (size_t)sidx * D_N) + c4*4;
      float4 k0 = Kp[0], k1 = Kp[1], k2 = Kp[2], k3 = Kp[3];
      float kv[16] = {k0.x,k0.y,k0.z,k0.w,k1.x,k1.y,k1.z,k1.w,
                      k2.x,k2.y,k2.z,k2.w,k3.x,k3.y,k3.z,k3.w};
      uint kh[16], klv[16];
      #pragma unroll
      for (int e = 0; e < 16; ++e){
        uint h = f2bf(kv[e]);
        kh[e] = h; klv[e] = f2bf(kv[e] - bf2f(h));
      }
      u32x4a H0 = (u32x4a){kh[0]|(kh[1]<<16),   kh[2]|(kh[3]<<16),
                           kh[4]|(kh[5]<<16),   kh[6]|(kh[7]<<16)};
      u32x4a H1 = (u32x4a){kh[8]|(kh[9]<<16),   kh[10]|(kh[11]<<16),
                           kh[12]|(kh[13]<<16), kh[14]|(kh[15]<<16)};
      u32x4a L0 = (u32x4a){klv[0]|(klv[1]<<16),   klv[2]|(klv[3]<<16),
                           klv[4]|(klv[5]<<16),   klv[6]|(klv[7]<<16)};
      u32x4a L1 = (u32x4a){klv[8]|(klv[9]<<16),   klv[10]|(klv[11]<<16),
                           klv[12]|(klv[13]<<16), klv[14]|(klv[15]<<16)};
      char* krh = (char*)Khi + jrow*128;
      char* krl = (char*)Klo + jrow*128;
      int o0 = ldsw(c4*32, jrow), o1 = ldsw(c4*32 + 16, jrow);
      *(u32x4a*)(krh + o0) = H0;  *(u32x4a*)(krh + o1) = H1;
      *(u32x4a*)(krl + o0) = L0;  *(u32x4a*)(krl + o1) = L1;

      float4 v0 = Vp[0], v1 = Vp[1], v2 = Vp[2], v3 = Vp[3];
      float vv[16] = {v0.x,v0.y,v0.z,v0.w,v1.x,v1.y,v1.z,v1.w,
                      v2.x,v2.y,v2.z,v2.w,v3.x,v3.y,v3.z,v3.w};
      #pragma unroll
      for (int e = 0; e < 16; ++e){
        int d = c4*16 + e;
        uint h  = f2bf(vv[e]);
        uint l2 = f2bf(vv[e] - bf2f(h));
        int off = d*144 + ldsw(jrow*2, d);
        *(ushort*)((char*)Vhi + off) = (ushort)h;
        *(ushort*)((char*)Vlo + off) = (ushort)l2;
      }
    }
    __syncthreads();

    const bool lastt = (tb == ntile - 1);
    #pragma unroll
    for (int qs = 0; qs < 2; ++qs){
      #pragma unroll
      for (int kt = 0; kt < 4; ++kt){
        int row = kt*16 + c;
        const char* krh = (const char*)Khi + row*128;
        const char* krl = (const char*)Klo + row*128;
        int e0 = ldsw(16*gi, row), e1 = ldsw(64 + 16*gi, row);
        bf16x8 kh0 = *(const bf16x8*)(krh + e0);
        bf16x8 kh1 = *(const bf16x8*)(krh + e1);
        bf16x8 kl0 = *(const bf16x8*)(krl + e0);
        bf16x8 kl1 = *(const bf16x8*)(krl + e1);
        f32x4 s = (f32x4){0.f,0.f,0.f,0.f};
        s = MFMA16(kh0, qh[qs][0], s, 0,0,0);
        s = MFMA16(kh1, qh[qs][1], s, 0,0,0);
        s = MFMA16(kh0, ql[qs][0], s, 0,0,0);
        s = MFMA16(kh1, ql[qs][1], s, 0,0,0);
        s = MFMA16(kl0, qh[qs][0], s, 0,0,0);
        s = MFMA16(kl1, qh[qs][1], s, 0,0,0);
        float pv[4];
        #pragma unroll
        for (int r = 0; r < 4; ++r){
          float t  = __builtin_amdgcn_exp2f(s[r] * 0.3606737602222409f);
          float wv = __builtin_amdgcn_rcpf(t + 1.0f);
          pv[r] = __builtin_amdgcn_exp2f(-28.853900817779268f * wv);
        }
        if (lastt){
          int kg0 = tb*KT + kt*16 + gi*4;
          #pragma unroll
          for (int r = 0; r < 4; ++r) if (kg0 + r >= cnt) pv[r] = 0.f;
        }
        zz[qs] += (pv[0] + pv[1]) + (pv[2] + pv[3]);
        uint h0 = f2bf(pv[0]), h1 = f2bf(pv[1]),
             h2 = f2bf(pv[2]), h3 = f2bf(pv[3]);
        uint l0 = f2bf(pv[0]-bf2f(h0)), l1 = f2bf(pv[1]-bf2f(h1)),
             l2 = f2bf(pv[2]-bf2f(h2)), l3 = f2bf(pv[3]-bf2f(h3));
        int ow = c*144 + ldsw(kt*32 + gi*8, c);
        *(u32x2a*)((char*)Ph + ow) = (u32x2a){h0|(h1<<16), h2|(h3<<16)};
        *(u32x2a*)((char*)Pl + ow) = (u32x2a){l0|(l1<<16), l2|(l3<<16)};
      }
      bf16x8 pah[2], pal[2];
      {
        const char* prh = (const char*)Ph + c*144;
        const char* prl = (const char*)Pl + c*144;
        #pragma unroll
        for (int ks = 0; ks < 2; ++ks){
          int oo = ldsw(64*ks + 16*gi, c);
          pah[ks] = *(const bf16x8*)(prh + oo);
          pal[ks] = *(const bf16x8*)(prl + oo);
        }
      }
      #pragma unroll
      for (int ds = 0; ds < 4; ++ds){
        int drow = ds*16 + c;
        const char* vrh = (const char*)Vhi + drow*144;
        const char* vrl = (const char*)Vlo + drow*144;
        f32x4 o = Oa[qs][ds];
        #pragma unroll
        for (int ks = 0; ks < 2; ++ks){
          int oo = ldsw(64*ks + 16*gi, drow);
          bf16x8 vh = *(const bf16x8*)(vrh + oo);
          bf16x8 vl = *(const bf16x8*)(vrl + oo);
          o = MFMA16(pah[ks], vh, o, 0,0,0);
          o = MFMA16(pah[ks], vl, o, 0,0,0);
          o = MFMA16(pal[ks], vh, o, 0,0,0);
        }
        Oa[qs][ds] = o;
      }
    }
    __syncthreads();
  }

  #pragma unroll
  for (int qs = 0; qs < 2; ++qs){
    float zt = zz[qs];
    zt += __shfl_xor(zt, 16);
    zt += __shfl_xor(zt, 32);
    float rz = 1.0f / zt;
    #pragma unroll
    for (int r = 0; r < 4; ++r){
      float rzq = __shfl(rz, gi*4 + r);
      size_t rowbase = ((size_t)bh * S_N + (size_t)(q0w + qs*16 + gi*4 + r)) * D_N;
      #pragma unroll
      for (int ds = 0; ds < 4; ++ds){
        Og[rowbase + ds*16 + c] = Oa[qs][ds][r] * rzq;
      }
    }
  }
}

extern "C" void kernel_launch(void* const* d_in, const int* in_sizes, int n_in,
                              void* d_out, int out_size, void* d_ws, size_t ws_size,
                              hipStream_t stream) {
  const float* Qg = (const float*)d_in[0];
  const float* Kg = (const float*)d_in[1];
  const float* Vg = (const float*)d_in[2];
  const int*   Mg = (const int*)d_in[3];
  float* Og = (float*)d_out;
  if (ws_size >= WS_NEED){
    int*    cnt_ws = (int*)d_ws;
    ushort* idx_ws = (ushort*)((char*)d_ws + 64);
    char*   img    = (char*)d_ws + IMG_OFF;
    compact_k<<<dim3(B_N), dim3(256), 0, stream>>>(Mg, cnt_ws, idx_ws);
    stage_k<<<dim3(B_N*H_N*MAXTILE), dim3(256), 0, stream>>>(Kg, Vg, cnt_ws, idx_ws, img);
    attn13_k<<<dim3(NBLK), dim3(256), 0, stream>>>(Qg, img, cnt_ws, Og);
  } else {
    attn_k<<<dim3(NBLK), dim3(256), 0, stream>>>(Qg, Kg, Vg, Mg, Og);
  }
}

// Round 15
// 133.701 us; speedup vs baseline: 1.2533x; 1.0000x over previous
//
#include <hip/hip_runtime.h>

typedef short bf16x8 __attribute__((ext_vector_type(8), may_alias));
typedef float f32x4 __attribute__((ext_vector_type(4)));
typedef unsigned int u32x4a __attribute__((ext_vector_type(4), may_alias));
typedef unsigned int u32x2a __attribute__((ext_vector_type(2), may_alias));
typedef unsigned short ushort;
typedef unsigned int uint;

#define B_N 4
#define H_N 16
#define S_N 2048
#define D_N 64
#define BQ 128      // q rows per block
#define WQ 32       // q rows per wave
#define KT 64       // key tile
#define NW 4        // waves per block
#define NBLK (B_N*H_N*(S_N/BQ))   // 1024 blocks
#define TILE_BYTES 32768          // image tile: Khi|Klo|VThi|VTlo, 8KB each (64 keys)
#define MAXTILE (S_N/KT)          // 32
#define IMG_OFF 32768
#define WS_NEED ((size_t)IMG_OFF + (size_t)B_N*H_N*MAXTILE*TILE_BYTES)

#define MFMA16 __builtin_amdgcn_mfma_f32_16x16x32_bf16

// f32 -> bf16 round-to-nearest-even (bit trick)
__device__ __forceinline__ uint f2bf(float x){
  uint u = __float_as_uint(x);
  u += 0x7fffu + ((u >> 16) & 1u);
  return u >> 16;
}
__device__ __forceinline__ float bf2f(uint h){
  return __uint_as_float(h << 16);
}
__device__ __forceinline__ int ldsw(int off, int row){
  return off ^ ((row & 7) << 4);
}
__device__ __forceinline__ void gload16(const void* g, void* l){
  __builtin_amdgcn_global_load_lds((const uint __attribute__((address_space(1)))*)g,
                                   (uint __attribute__((address_space(3)))*)l, 16, 0, 0);
}

// ---------------- pre-pass A: per-b mask compaction ----------------
__global__ __launch_bounds__(256)
void compact_k(const int* __restrict__ Mg, int* __restrict__ cnt_ws,
               ushort* __restrict__ idx_ws)
{
  __shared__ int sws[NW];
  const int b = blockIdx.x;
  const int tid = threadIdx.x, lane = tid & 63, w = tid >> 6;
  const int* mb = Mg + (size_t)b * S_N;
  int kept[8]; int cl = 0; int base = tid * 8;
  #pragma unroll
  for (int i = 0; i < 8; ++i){ kept[i] = (mb[base+i] == 0); cl += kept[i]; }
  int inc = cl;
  #pragma unroll
  for (int d = 1; d < 64; d <<= 1){
    int o = __shfl_up(inc, d);
    if (lane >= d) inc += o;
  }
  if (lane == 63) sws[w] = inc;
  __syncthreads();
  int s0 = sws[0], s1 = sws[1], s2 = sws[2], s3 = sws[3];
  int wo = (w > 0 ? s0 : 0) + (w > 1 ? s1 : 0) + (w > 2 ? s2 : 0);
  int pos = wo + inc - cl;
  #pragma unroll
  for (int i = 0; i < 8; ++i){
    if (kept[i]) idx_ws[b*S_N + pos++] = (ushort)(base + i);
  }
  if (tid == 0) cnt_ws[b] = s0 + s1 + s2 + s3;
}

// ---------------- pre-pass B: gather + convert + build LDS images ----------------
// K image (per 64-key tile): rows jrow*128B, 16B granules XOR-swizzled by (jrow&7).
// V^T image: row d = 128B = [half0 64B | half1 64B]; 16B chunk g of half h holds
// elements e = V[h*32 + kap(g,e)][d], kap(g,e) = g*4+(e&3) + 16*(e>>2).
// kap matches the MFMA C-layout key positions so P needs NO redistribution.
__global__ __launch_bounds__(256)
void stage_k(const float* __restrict__ Kg, const float* __restrict__ Vg,
             const int* __restrict__ cnt_ws, const ushort* __restrict__ idx_ws,
             char* __restrict__ img)
{
  __shared__ float Vl[64*65];
  const int bid = blockIdx.x;
  const int bh = bid >> 5;
  const int tile = bid & 31;
  const int b = bh >> 4;
  const int cnt = cnt_ws[b];
  const int ntile = (cnt + 63) >> 6;
  if (tile >= ntile) return;
  const int tid = threadIdx.x;
  char* G = img + (size_t)bid * TILE_BYTES;

  const int jrow = tid >> 2, c4 = tid & 3;
  int kk = tile*64 + jrow; if (kk >= cnt) kk = cnt - 1;
  const int sidx = idx_ws[b*S_N + kk];
  const size_t kvbase = (size_t)bh * (size_t)(S_N*D_N);
  const int sw = (jrow & 7) << 4;
  {
    const float4* Kp = (const float4*)(Kg + kvbase + (size_t)sidx*D_N) + c4*4;
    float4 k0 = Kp[0], k1 = Kp[1], k2 = Kp[2], k3 = Kp[3];
    float kv[16] = {k0.x,k0.y,k0.z,k0.w,k1.x,k1.y,k1.z,k1.w,
                    k2.x,k2.y,k2.z,k2.w,k3.x,k3.y,k3.z,k3.w};
    uint h[16], l[16];
    #pragma unroll
    for (int e = 0; e < 16; ++e){
      uint hh = f2bf(kv[e]); h[e] = hh; l[e] = f2bf(kv[e] - bf2f(hh));
    }
    char* r0 = G + jrow*128;
    char* r1 = G + 8192 + jrow*128;
    *(u32x4a*)(r0 + ((c4*32)      ^ sw)) = (u32x4a){h[0]|(h[1]<<16),  h[2]|(h[3]<<16),
                                                    h[4]|(h[5]<<16),  h[6]|(h[7]<<16)};
    *(u32x4a*)(r0 + ((c4*32 + 16) ^ sw)) = (u32x4a){h[8]|(h[9]<<16),  h[10]|(h[11]<<16),
                                                    h[12]|(h[13]<<16),h[14]|(h[15]<<16)};
    *(u32x4a*)(r1 + ((c4*32)      ^ sw)) = (u32x4a){l[0]|(l[1]<<16),  l[2]|(l[3]<<16),
                                                    l[4]|(l[5]<<16),  l[6]|(l[7]<<16)};
    *(u32x4a*)(r1 + ((c4*32 + 16) ^ sw)) = (u32x4a){l[8]|(l[9]<<16),  l[10]|(l[11]<<16),
                                                    l[12]|(l[13]<<16),l[14]|(l[15]<<16)};
  }
  {
    const float4* Vp = (const float4*)(Vg + kvbase + (size_t)sidx*D_N) + c4*4;
    float4 v0 = Vp[0], v1 = Vp[1], v2 = Vp[2], v3 = Vp[3];
    float vv[16] = {v0.x,v0.y,v0.z,v0.w,v1.x,v1.y,v1.z,v1.w,
                    v2.x,v2.y,v2.z,v2.w,v3.x,v3.y,v3.z,v3.w};
    #pragma unroll
    for (int e = 0; e < 16; ++e) Vl[jrow*65 + c4*16 + e] = vv[e];
  }
  __syncthreads();
  // V^T image with kap ordering: 512 granules (d 0..63, h 0..1, g 0..3)
  #pragma unroll
  for (int t = 0; t < 2; ++t){
    int idx2 = tid + t*256;
    int d = idx2 >> 3;
    int h = (idx2 >> 2) & 1;
    int g = idx2 & 3;
    int kb = h*32 + g*4;
    uint hh[8], ll[8];
    #pragma unroll
    for (int e = 0; e < 8; ++e){
      int k = kb + (e & 3) + ((e >> 2) << 4);   // kap(g,e) within half
      float x = Vl[k*65 + d];
      uint hv = f2bf(x); hh[e] = hv; ll[e] = f2bf(x - bf2f(hv));
    }
    *(u32x4a*)(G + 16384 + d*128 + h*64 + g*16) =
        (u32x4a){hh[0]|(hh[1]<<16), hh[2]|(hh[3]<<16), hh[4]|(hh[5]<<16), hh[6]|(hh[7]<<16)};
    *(u32x4a*)(G + 24576 + d*128 + h*64 + g*16) =
        (u32x4a){ll[0]|(ll[1]<<16), ll[2]|(ll[3]<<16), ll[4]|(ll[5]<<16), ll[6]|(ll[7]<<16)};
  }
}

// ---------------- main attention kernel: r13 FINAL (restored verbatim) ----------------
// Best passing artifact: 133.7us total, absmax 1.953125e-3, bank conflicts 0.
// Full 64-key tiles (32 barriers), K rows XOR-swizzled, V^T 128B rows swizzled
// via pre-swizzled gload_lds source, P-in-registers via kap bitcast, 3-pass
// split-precision QK^T and PV. __launch_bounds__(256,2): (256,4) miscompiles
// (r3/r11); softmax VALU-cut variants miscompile (r8/r12/r14 — NaN/0.9 errors
// from analytically-sound edits). This structure is the toolchain-stable peak.
__global__ __launch_bounds__(256, 2)
void attn13_k(const float* __restrict__ Qg, const char* __restrict__ img,
              const int* __restrict__ cnt_ws, float* __restrict__ Og)
{
  __shared__ __align__(16) char smem[2][32768];  // [buf][Khi 8K|Klo 8K|VThi 8K|VTlo 8K]

  const int tid  = threadIdx.x;
  const int lane = tid & 63;
  const int w    = tid >> 6;
  const int c    = lane & 15;
  const int gi   = lane >> 4;

  int bid = blockIdx.x;
  int wg  = (bid & 7) * (NBLK/8) + (bid >> 3);
  int qt  = wg & 15;
  int bh  = wg >> 4;
  int b   = bh >> 4;

  const int cnt = cnt_ws[b];
  const int ntile = (cnt + 63) >> 6;
  const char* Gb = img + (size_t)bh * MAXTILE * TILE_BYTES;

  // stage full tile t into buffer sb: per-lane SOURCE addr, wave-uniform LDS dest
  auto stage = [&](int t, int sb){
    const char* T = Gb + (size_t)t * TILE_BYTES;
    char* Bse = (char*)&smem[sb][0];
    if (w < 2){
      // K hi (w=0) / lo (w=1): linear 8KB copy
      const char* src = T + w*8192 + lane*16;
      char* dst = Bse + w*8192;
      #pragma unroll
      for (int i = 0; i < 8; ++i) gload16(src + i*1024, dst + i*1024);
    } else {
      // V^T hi (w=2) / lo (w=3): linear dest; source pre-swizzled so that
      // lds[d*128 + off] = img[d*128 + (off ^ ((d&7)<<4))]
      const int hl = w - 2;
      const char* base = T + 16384 + hl*8192;
      char* dst = Bse + 16384 + hl*8192;
      #pragma unroll
      for (int i = 0; i < 8; ++i){
        int pos = i*1024 + lane*16;
        int d = pos >> 7;
        int off = pos & 127;
        gload16(base + d*128 + (off ^ ((d & 7) << 4)), dst + i*1024);
      }
    }
  };

  if (ntile > 0) stage(0, 0);

  // Q fragments hi/lo in registers (B-operand of swapped QK^T)
  const int q0w = qt * BQ + w * WQ;
  bf16x8 qh[2][2], ql[2][2];
  {
    const float* Qbase = Qg + (size_t)bh * S_N * D_N;
    #pragma unroll
    for (int qs = 0; qs < 2; ++qs){
      const float* qr = Qbase + (size_t)(q0w + qs*16 + c) * D_N;
      #pragma unroll
      for (int ks = 0; ks < 2; ++ks){
        const float4* p4 = (const float4*)(qr + ks*32 + gi*8);
        float4 x0 = p4[0], x1 = p4[1];
        float xs[8] = {x0.x,x0.y,x0.z,x0.w,x1.x,x1.y,x1.z,x1.w};
        union { bf16x8 v; ushort u[8]; } uh, ul;
        #pragma unroll
        for (int e = 0; e < 8; ++e){
          uint h = f2bf(xs[e]);
          uh.u[e] = (ushort)h;
          ul.u[e] = (ushort)f2bf(xs[e] - bf2f(h));
        }
        qh[qs][ks] = uh.v; ql[qs][ks] = ul.v;
      }
    }
  }

  f32x4 Oa[2][4];
  #pragma unroll
  for (int i = 0; i < 2; ++i)
    #pragma unroll
    for (int jj = 0; jj < 4; ++jj)
      Oa[i][jj] = (f32x4){0.f,0.f,0.f,0.f};
  float zz[2] = {0.f, 0.f};

  const int swc16 = (c & 7) << 4;
  const int e0 = (gi*16) ^ swc16;
  const int e1 = (64 + gi*16) ^ swc16;

  __syncthreads();

  for (int tb = 0; tb < ntile; ++tb){
    const int buf = tb & 1;
    if (tb + 1 < ntile) stage(tb + 1, buf ^ 1);
    const char* Khi  = &smem[buf][0];
    const char* Klo  = Khi + 8192;
    const char* VThi = Khi + 16384;
    const char* VTlo = Khi + 24576;
    const bool lastt = (tb == ntile - 1);

    uint sH[2][8], sL[2][8];   // [qs][kt*2 + word]
    #pragma unroll
    for (int kt = 0; kt < 4; ++kt){
      int row = kt*16 + c;
      const char* krh = Khi + row*128;
      const char* krl = Klo + row*128;
      bf16x8 kh0 = *(const bf16x8*)(krh + e0);
      bf16x8 kh1 = *(const bf16x8*)(krh + e1);
      bf16x8 kl0 = *(const bf16x8*)(krl + e0);
      bf16x8 kl1 = *(const bf16x8*)(krl + e1);
      #pragma unroll
      for (int qs = 0; qs < 2; ++qs){
        f32x4 s = (f32x4){0.f,0.f,0.f,0.f};
        s = MFMA16(kh0, qh[qs][0], s, 0,0,0);
        s = MFMA16(kh1, qh[qs][1], s, 0,0,0);
        s = MFMA16(kh0, ql[qs][0], s, 0,0,0);
        s = MFMA16(kh1, ql[qs][1], s, 0,0,0);
        s = MFMA16(kl0, qh[qs][0], s, 0,0,0);
        s = MFMA16(kl1, qh[qs][1], s, 0,0,0);
        // p = exp(10*tanh(s/8) - 10) = exp2(-28.8539 / (exp2(s*0.360674)+1))
        float pv[4];
        #pragma unroll
        for (int r = 0; r < 4; ++r){
          float t  = __builtin_amdgcn_exp2f(s[r] * 0.3606737602222409f);
          float wv = __builtin_amdgcn_rcpf(t + 1.0f);
          pv[r] = __builtin_amdgcn_exp2f(-28.853900817779268f * wv);
        }
        if (lastt){
          int kg0 = tb*64 + kt*16 + gi*4;
          #pragma unroll
          for (int r = 0; r < 4; ++r) if (kg0 + r >= cnt) pv[r] = 0.f;
        }
        zz[qs] += (pv[0] + pv[1]) + (pv[2] + pv[3]);
        uint hA, hB, lA, lB;
        asm("v_cvt_pk_bf16_f32 %0, %1, %2" : "=v"(hA) : "v"(pv[0]), "v"(pv[1]));
        asm("v_cvt_pk_bf16_f32 %0, %1, %2" : "=v"(hB) : "v"(pv[2]), "v"(pv[3]));
        float l0 = pv[0] - __uint_as_float(hA << 16);
        float l1 = pv[1] - __uint_as_float(hA & 0xffff0000u);
        float l2 = pv[2] - __uint_as_float(hB << 16);
        float l3 = pv[3] - __uint_as_float(hB & 0xffff0000u);
        asm("v_cvt_pk_bf16_f32 %0, %1, %2" : "=v"(lA) : "v"(l0), "v"(l1));
        asm("v_cvt_pk_bf16_f32 %0, %1, %2" : "=v"(lB) : "v"(l2), "v"(l3));
        sH[qs][kt*2+0] = hA; sH[qs][kt*2+1] = hB;
        sL[qs][kt*2+0] = lA; sL[qs][kt*2+1] = lB;
      }
    }
    // P fragments: pure bitcast (k-order kap matches the V^T image); half h
    // covers keys h*32..h*32+31 = kt 2h,2h+1 -> words sH[qs][4h..4h+3]
    union PU { u32x4a g; bf16x8 v; };
    PU pah[2][2], pal[2][2];
    #pragma unroll
    for (int qs = 0; qs < 2; ++qs){
      #pragma unroll
      for (int h = 0; h < 2; ++h){
        pah[qs][h].g = (u32x4a){sH[qs][4*h+0], sH[qs][4*h+1], sH[qs][4*h+2], sH[qs][4*h+3]};
        pal[qs][h].g = (u32x4a){sL[qs][4*h+0], sL[qs][4*h+1], sL[qs][4*h+2], sL[qs][4*h+3]};
      }
    }
    #pragma unroll
    for (int ds = 0; ds < 4; ++ds){
      int drow = ds*16 + c;
      const char* vbh = VThi + drow*128;
      const char* vbl = VTlo + drow*128;
      #pragma unroll
      for (int h = 0; h < 2; ++h){
        int vo = (h*64 + gi*16) ^ swc16;   // drow&7 == c&7
        bf16x8 vh = *(const bf16x8*)(vbh + vo);
        bf16x8 vl = *(const bf16x8*)(vbl + vo);
        #pragma unroll
        for (int qs = 0; qs < 2; ++qs){
          f32x4 o = Oa[qs][ds];
          o = MFMA16(pah[qs][h].v, vh, o, 0,0,0);
          o = MFMA16(pah[qs][h].v, vl, o, 0,0,0);
          o = MFMA16(pal[qs][h].v, vh, o, 0,0,0);
          Oa[qs][ds] = o;
        }
      }
    }
    __syncthreads();
  }

  // ---------- epilogue ----------
  #pragma unroll
  for (int qs = 0; qs < 2; ++qs){
    float zt = zz[qs];
    zt += __shfl_xor(zt, 16);
    zt += __shfl_xor(zt, 32);
    float rz = 1.0f / zt;
    #pragma unroll
    for (int r = 0; r < 4; ++r){
      float rzq = __shfl(rz, gi*4 + r);
      size_t rowbase = ((size_t)bh * S_N + (size_t)(q0w + qs*16 + gi*4 + r)) * D_N;
      #pragma unroll
      for (int ds = 0; ds < 4; ++ds){
        Og[rowbase + ds*16 + c] = Oa[qs][ds][r] * rzq;
      }
    }
  }
}

// ---------------- fallback (round-1 kernel, self-staging) ----------------
__global__ __launch_bounds__(256, 2)
void attn_k(const float* __restrict__ Qg, const float* __restrict__ Kg,
            const float* __restrict__ Vg, const int* __restrict__ Mg,
            float* __restrict__ Og)
{
  __shared__ __align__(16) ushort Khi[KT*D_N];
  __shared__ __align__(16) ushort Klo[KT*D_N];
  __shared__ __align__(16) ushort Vhi[D_N*72];
  __shared__ __align__(16) ushort Vlo[D_N*72];
  __shared__ __align__(16) ushort Phl[NW*16*72];
  __shared__ __align__(16) ushort Pll[NW*16*72];
  __shared__ ushort idx_l[S_N];
  __shared__ int scan_ws[NW];

  const int tid  = threadIdx.x;
  const int lane = tid & 63;
  const int w    = tid >> 6;
  const int c    = lane & 15;
  const int gi   = lane >> 4;

  int bid = blockIdx.x;
  int wg  = (bid & 7) * (NBLK/8) + (bid >> 3);
  int qt  = wg & 15;
  int bh  = wg >> 4;
  int b   = bh >> 4;

  int cnt;
  {
    const int* mb = Mg + (size_t)b * S_N;
    int kept[8]; int cl = 0;
    int base = tid * 8;
    #pragma unroll
    for (int i = 0; i < 8; ++i){ kept[i] = (mb[base+i] == 0); cl += kept[i]; }
    int inc = cl;
    #pragma unroll
    for (int d = 1; d < 64; d <<= 1){
      int o = __shfl_up(inc, d);
      if (lane >= d) inc += o;
    }
    if (lane == 63) scan_ws[w] = inc;
    __syncthreads();
    int s0 = scan_ws[0], s1 = scan_ws[1], s2 = scan_ws[2], s3 = scan_ws[3];
    int wo = (w > 0 ? s0 : 0) + (w > 1 ? s1 : 0) + (w > 2 ? s2 : 0);
    cnt = s0 + s1 + s2 + s3;
    int pos = wo + inc - cl;
    #pragma unroll
    for (int i = 0; i < 8; ++i){
      if (kept[i]) idx_l[pos++] = (ushort)(base + i);
    }
    __syncthreads();
  }

  const int q0w = qt * BQ + w * WQ;
  bf16x8 qh[2][2], ql[2][2];
  {
    const float* Qbase = Qg + (size_t)bh * S_N * D_N;
    #pragma unroll
    for (int qs = 0; qs < 2; ++qs){
      const float* qr = Qbase + (size_t)(q0w + qs*16 + c) * D_N;
      #pragma unroll
      for (int ks = 0; ks < 2; ++ks){
        const float4* p4 = (const float4*)(qr + ks*32 + gi*8);
        float4 x0 = p4[0], x1 = p4[1];
        float xs[8] = {x0.x,x0.y,x0.z,x0.w,x1.x,x1.y,x1.z,x1.w};
        union { bf16x8 v; ushort u[8]; } uh, ul;
        #pragma unroll
        for (int e = 0; e < 8; ++e){
          uint h = f2bf(xs[e]);
          uh.u[e] = (ushort)h;
          ul.u[e] = (ushort)f2bf(xs[e] - bf2f(h));
        }
        qh[qs][ks] = uh.v; ql[qs][ks] = ul.v;
      }
    }
  }

  f32x4 Oa[2][4];
  #pragma unroll
  for (int i = 0; i < 2; ++i)
    #pragma unroll
    for (int jj = 0; jj < 4; ++jj)
      Oa[i][jj] = (f32x4){0.f,0.f,0.f,0.f};
  float zz[2] = {0.f, 0.f};

  ushort* Ph = Phl + w * (16*72);
  ushort* Pl = Pll + w * (16*72);

  const int jrow = tid >> 2;
  const int c4   = tid & 3;
  const size_t kvbase = (size_t)bh * S_N * D_N;

  const int ntile = (cnt + KT - 1) >> 6;
  for (int tb = 0; tb < ntile; ++tb){
    {
      int kk = tb*KT + jrow;
      int ci = kk < cnt ? kk : cnt - 1;
      int sidx = idx_l[ci];
      const float4* Kp = (const float4*)(Kg + kvbase + (size_t)sidx * D_N) + c4*4;
      const float4* Vp = (const float4*)(Vg + kvbase + (size_t)sidx * D_N) + c4*4;
      float4 k0 = Kp[0], k1 = Kp[1], k2 = Kp[2], k3 = Kp[3];
      float kv[16] = {k0.x,k0.y,k0.z,k0.w,k1.x,k1.y,k1.z,k1.w,
                      k2.x,k2.y,k2.z,k2.w,k3.x,k3.y,k3.z,k3.w};
      uint kh[16], klv[16];
      #pragma unroll
      for (int e = 0; e < 16; ++e){
        uint h = f2bf(kv[e]);
        kh[e] = h; klv[e] = f2bf(kv[e] - bf2f(h));
      }
      u32x4a H0 = (u32x4a){kh[0]|(kh[1]<<16),   kh[2]|(kh[3]<<16),
                           kh[4]|(kh[5]<<16),   kh[6]|(kh[7]<<16)};
      u32x4a H1 = (u32x4a){kh[8]|(kh[9]<<16),   kh[10]|(kh[11]<<16),
                           kh[12]|(kh[13]<<16), kh[14]|(kh[15]<<16)};
      u32x4a L0 = (u32x4a){klv[0]|(klv[1]<<16),   klv[2]|(klv[3]<<16),
                           klv[4]|(klv[5]<<16),   klv[6]|(klv[7]<<16)};
      u32x4a L1 = (u32x4a){klv[8]|(klv[9]<<16),   klv[10]|(klv[11]<<16),
                           klv[12]|(klv[13]<<16), klv[14]|(klv[15]<<16)};
      char* krh = (char*)Khi + jrow*128;
      char* krl = (char*)Klo + jrow*128;
      int o0 = ldsw(c4*32, jrow), o1 = ldsw(c4*32 + 16, jrow);
      *(u32x4a*)(krh + o0) = H0;  *(u32x4a*)(krh + o1) = H1;
      *(u32x4a*)(krl + o0) = L0;  *(u32x4a*)(krl + o1) = L1;

      float4 v0 = Vp[0], v1 = Vp[1], v2 = Vp[2], v3 = Vp[3];
      float vv[16] = {v0.x,v0.y,v0.z,v0.w,v1.x,v1.y,v1.z,v1.w,
                      v2.x,v2.y,v2.z,v2.w,v3.x,v3.y,v3.z,v3.w};
      #pragma unroll
      for (int e = 0; e < 16; ++e){
        int d = c4*16 + e;
        uint h  = f2bf(vv[e]);
        uint l2 = f2bf(vv[e] - bf2f(h));
        int off = d*144 + ldsw(jrow*2, d);
        *(ushort*)((char*)Vhi + off) = (ushort)h;
        *(ushort*)((char*)Vlo + off) = (ushort)l2;
      }
    }
    __syncthreads();

    const bool lastt = (tb == ntile - 1);
    #pragma unroll
    for (int qs = 0; qs < 2; ++qs){
      #pragma unroll
      for (int kt = 0; kt < 4; ++kt){
        int row = kt*16 + c;
        const char* krh = (const char*)Khi + row*128;
        const char* krl = (const char*)Klo + row*128;
        int e0 = ldsw(16*gi, row), e1 = ldsw(64 + 16*gi, row);
        bf16x8 kh0 = *(const bf16x8*)(krh + e0);
        bf16x8 kh1 = *(const bf16x8*)(krh + e1);
        bf16x8 kl0 = *(const bf16x8*)(krl + e0);
        bf16x8 kl1 = *(const bf16x8*)(krl + e1);
        f32x4 s = (f32x4){0.f,0.f,0.f,0.f};
        s = MFMA16(kh0, qh[qs][0], s, 0,0,0);
        s = MFMA16(kh1, qh[qs][1], s, 0,0,0);
        s = MFMA16(kh0, ql[qs][0], s, 0,0,0);
        s = MFMA16(kh1, ql[qs][1], s, 0,0,0);
        s = MFMA16(kl0, qh[qs][0], s, 0,0,0);
        s = MFMA16(kl1, qh[qs][1], s, 0,0,0);
        float pv[4];
        #pragma unroll
        for (int r = 0; r < 4; ++r){
          float t  = __builtin_amdgcn_exp2f(s[r] * 0.3606737602222409f);
          float wv = __builtin_amdgcn_rcpf(t + 1.0f);
          pv[r] = __builtin_amdgcn_exp2f(-28.853900817779268f * wv);
        }
        if (lastt){
          int kg0 = tb*KT + kt*16 + gi*4;
          #pragma unroll
          for (int r = 0; r < 4; ++r) if (kg0 + r >= cnt) pv[r] = 0.f;
        }
        zz[qs] += (pv[0] + pv[1]) + (pv[2] + pv[3]);
        uint h0 = f2bf(pv[0]), h1 = f2bf(pv[1]),
             h2 = f2bf(pv[2]), h3 = f2bf(pv[3]);
        uint l0 = f2bf(pv[0]-bf2f(h0)), l1 = f2bf(pv[1]-bf2f(h1)),
             l2 = f2bf(pv[2]-bf2f(h2)), l3 = f2bf(pv[3]-bf2f(h3));
        int ow = c*144 + ldsw(kt*32 + gi*8, c);
        *(u32x2a*)((char*)Ph + ow) = (u32x2a){h0|(h1<<16), h2|(h3<<16)};
        *(u32x2a*)((char*)Pl + ow) = (u32x2a){l0|(l1<<16), l2|(l3<<16)};
      }
      bf16x8 pah[2], pal[2];
      {
        const char* prh = (const char*)Ph + c*144;
        const char* prl = (const char*)Pl + c*144;
        #pragma unroll
        for (int ks = 0; ks < 2; ++ks){
          int oo = ldsw(64*ks + 16*gi, c);
          pah[ks] = *(const bf16x8*)(prh + oo);
          pal[ks] = *(const bf16x8*)(prl + oo);
        }
      }
      #pragma unroll
      for (int ds = 0; ds < 4; ++ds){
        int drow = ds*16 + c;
        const char* vrh = (const char*)Vhi + drow*144;
        const char* vrl = (const char*)Vlo + drow*144;
        f32x4 o = Oa[qs][ds];
        #pragma unroll
        for (int ks = 0; ks < 2; ++ks){
          int oo = ldsw(64*ks + 16*gi, drow);
          bf16x8 vh = *(const bf16x8*)(vrh + oo);
          bf16x8 vl = *(const bf16x8*)(vrl + oo);
          o = MFMA16(pah[ks], vh, o, 0,0,0);
          o = MFMA16(pah[ks], vl, o, 0,0,0);
          o = MFMA16(pal[ks], vh, o, 0,0,0);
        }
        Oa[qs][ds] = o;
      }
    }
    __syncthreads();
  }

  #pragma unroll
  for (int qs = 0; qs < 2; ++qs){
    float zt = zz[qs];
    zt += __shfl_xor(zt, 16);
    zt += __shfl_xor(zt, 32);
    float rz = 1.0f / zt;
    #pragma unroll
    for (int r = 0; r < 4; ++r){
      float rzq = __shfl(rz, gi*4 + r);
      size_t rowbase = ((size_t)bh * S_N + (size_t)(q0w + qs*16 + gi*4 + r)) * D_N;
      #pragma unroll
      for (int ds = 0; ds < 4; ++ds){
        Og[rowbase + ds*16 + c] = Oa[qs][ds][r] * rzq;
      }
    }
  }
}

extern "C" void kernel_launch(void* const* d_in, const int* in_sizes, int n_in,
                              void* d_out, int out_size, void* d_ws, size_t ws_size,
                              hipStream_t stream) {
  const float* Qg = (const float*)d_in[0];
  const float* Kg = (const float*)d_in[1];
  const float* Vg = (const float*)d_in[2];
  const int*   Mg = (const int*)d_in[3];
  float* Og = (float*)d_out;
  if (ws_size >= WS_NEED){
    int*    cnt_ws = (int*)d_ws;
    ushort* idx_ws = (ushort*)((char*)d_ws + 64);
    char*   img    = (char*)d_ws + IMG_OFF;
    compact_k<<<dim3(B_N), dim3(256), 0, stream>>>(Mg, cnt_ws, idx_ws);
    stage_k<<<dim3(B_N*H_N*MAXTILE), dim3(256), 0, stream>>>(Kg, Vg, cnt_ws, idx_ws, img);
    attn13_k<<<dim3(NBLK), dim3(256), 0, stream>>>(Qg, img, cnt_ws, Og);
  } else {
    attn_k<<<dim3(NBLK), dim3(256), 0, stream>>>(Qg, Kg, Vg, Mg, Og);
  }
}